// Round 4
// baseline (224.387 us; speedup 1.0000x reference)
//
#include <hip/hip_runtime.h>

// GraphAttention: B=4, N=2048, F=256, H=8, F_=64; out [B, N, 512].
// 3 dispatches:
//  k_mask_conv: A -> expanded fp16-mask plane M16 (0xFFFF per edge) +
//               init maxn; W -> bf16 MFMA B-fragment layout Wf.
//  k_gemm1    : h=X@W (MFMA, raw X converted to bf16 in-register) + att
//               epilogue (att_s f32; E=exp(pn), E5=exp(0.2pn) fp16 planes;
//               per-bh max(att_n)) + LDS repack of h into MFMA fragment
//               layout hswz[bh][jc][ct][lane][8] (FP16 now).
//  k_attn_av  : fused masked softmax @ h, all-fp16 P path:
//               per 2 cols: v_pk_mul_f16(k1,E) / v_pk_mul_f16(k2,E5) /
//               v_pk_max_f16 / AND M16 -> packed A-frag, mfma f16.
//               2 VALU per (i,j) vs 5.5 before (P-materialization was the
//               measured 43-us VALU floor @ r17: VALUBusy 53%, Mfma 14%).
// History: r9 global-atomic j-split -> 425MB HBM (never); r11/r15
// launch_bounds min-waves 6 -> VGPR cap 40 -> spills (KEEP CAP >= 128:
// 2nd arg <= 4 at 256 thr). r14 199.9us; r16 202.9 (attn 57); r17 207.3
// (attn 58; non-attn ~145-149us INVARIANT across mask/gemm rewrites ->
// suspect fixed overhead; this round halves attn's VALU floor via fp16
// packed math + pre-expanded mask).
// Input dtype detected from A[0][0] (self-loop: fp32 word == 1.0f).
// Workspace use: ~42.8 MB (M16 expanded mask is 32 MB).

constexpr int GN  = 2048;
constexpr int GHF = 512;

using sh8    = __attribute__((ext_vector_type(8))) short;          // 8x16b
using hf8    = __attribute__((ext_vector_type(8))) _Float16;       // 8 fp16
using us4g   = __attribute__((ext_vector_type(4))) unsigned short;
using f32x4g = __attribute__((ext_vector_type(4))) float;
using u32x4g = __attribute__((ext_vector_type(4))) unsigned int;
using i32x4g = __attribute__((ext_vector_type(4))) int;

__device__ inline float gat_bf2f(unsigned short u) {
    union { unsigned int i; float f; } c; c.i = ((unsigned int)u) << 16; return c.f;
}
__device__ inline unsigned short gat_f2bf(float f) {
    union { float f; unsigned int i; } c; c.f = f;
    return (unsigned short)((c.i + 0x7fffu + ((c.i >> 16) & 1u)) >> 16); // RNE
}
__device__ inline unsigned short gat_f2h(float f) {
    _Float16 h = (_Float16)f;
    union { _Float16 h; unsigned short u; } c; c.h = h; return c.u;
}
__device__ inline float gat_h2f(unsigned short u) {
    union { _Float16 h; unsigned short u; } c; c.u = u; return (float)c.h;
}
__device__ inline int gat_isf32(const float* __restrict__ Aw) {
    float a = Aw[0];
    return (a == 0.0f) || (a == 1.0f);
}
__device__ inline unsigned int gat_enc(float f) {
    union { float f; unsigned int u; } c; c.f = f;
    return (c.u & 0x80000000u) ? ~c.u : (c.u | 0x80000000u);
}
__device__ inline float gat_dec(unsigned int e) {
    union { float f; unsigned int u; } c;
    c.u = (e & 0x80000000u) ? (e & 0x7fffffffu) : ~e;
    return c.f;
}
// fragment-layout accessor (scalar, fallback paths):
// h[o][j] of head-slice -> flat elem index in hswz (per-bh base excluded)
__device__ inline size_t gat_hswz_idx(int o, int j) {
    int jc = j >> 5, quad = (j >> 3) & 3, e = j & 7;
    int lane = quad * 16 + (o & 15);
    return (((size_t)(jc * 4 + (o >> 4))) * 64 + lane) * 8 + e;
}
// W fragment layout accessor: W[hh][k][col] -> flat index in Wf
__device__ inline size_t gat_wf_idx(int hh, int k, int col) {
    int kg = k >> 5, quad = (k >> 3) & 3, e = k & 7;
    int ct = col >> 4, lrw = col & 15;
    return ((((size_t)hh * 8 + kg) * 4 + ct) * 64 + (quad * 16 + lrw)) * 8 + e;
}

__global__ void GraphAttention_62981400429165_kernel() {}

// ---------------- workspace layout (bytes) ----------------
constexpr size_t OFF_HS   = 256;                       // hswz fp16      8 MB
constexpr size_t OFF_ATTS = OFF_HS   + 8388608;        // att_s f32    256 KB
constexpr size_t OFF_EF   = OFF_ATTS + 262144;         // E  fp16      128 KB
constexpr size_t OFF_E5F  = OFF_EF   + 131072;         // E5 fp16      128 KB
constexpr size_t OFF_M16  = OFF_E5F  + 131072;         // mask ushort   32 MB
constexpr size_t OFF_MAXN = OFF_M16  + 33554432;       // 32 u32
constexpr size_t OFF_WC   = OFF_MAXN + 256;            // Wf bf16      256 KB

// --------------------------------------------------------------------------
// k_mask_conv: blocks 0..8191: A -> M16 expanded mask (ushort 0xFFFF/0)
// (+block 0 inits maxn). 8192..8255: W -> Wf fragment layout.
// --------------------------------------------------------------------------
__global__ __launch_bounds__(256) void k_mask_conv(const void* __restrict__ Araw,
                                                   const void* __restrict__ Wraw,
                                                   unsigned short* __restrict__ M16,
                                                   unsigned int* __restrict__ maxn_enc,
                                                   unsigned short* __restrict__ Wf) {
    int tid = threadIdx.x, blk = blockIdx.x;
    int isf = gat_isf32((const float*)Araw);
    if (blk < 8192) {
        if (blk == 0 && tid < 32) maxn_enc[tid] = 0u;
        size_t i8 = ((size_t)blk * 256 + tid) * 8;     // 8 A elems / thread
        u32x4g mo;
        if (isf) {
            f32x4g v0 = *(const f32x4g*)((const float*)Araw + i8);
            f32x4g v1 = *(const f32x4g*)((const float*)Araw + i8 + 4);
            float el[8] = {v0[0], v0[1], v0[2], v0[3], v1[0], v1[1], v1[2], v1[3]};
#pragma unroll
            for (int p = 0; p < 4; p++)
                mo[p] = (el[2 * p]     != 0.0f ? 0x0000FFFFu : 0u)
                      | (el[2 * p + 1] != 0.0f ? 0xFFFF0000u : 0u);
        } else {
            u32x4g v = *(const u32x4g*)((const unsigned short*)Araw + i8);
#pragma unroll
            for (int p = 0; p < 4; p++)
                mo[p] = ((v[p] & 0xffffu) != 0u ? 0x0000FFFFu : 0u)
                      | ((v[p] >> 16)    != 0u ? 0xFFFF0000u : 0u);
        }
        *(u32x4g*)((unsigned int*)M16 + (i8 >> 1)) = mo;
    } else {
        // W -> fragment layout. gid = hh*2048 + kg*256 + ct*64 + lane.
        int gid = (blk - 8192) * 256 + tid;          // [0, 16384)
        int lane = gid & 63, ct = (gid >> 6) & 3, kg = (gid >> 8) & 7, hh = gid >> 11;
        int quad = lane >> 4, lrw = lane & 15;
        int col = ct * 16 + lrw;
        us4g lo, hi;
#pragma unroll
        for (int e = 0; e < 8; e++) {
            int k = kg * 32 + quad * 8 + e;
            size_t src = (size_t)hh * 16384 + (size_t)k * 64 + col;
            unsigned short v = isf ? gat_f2bf(((const float*)Wraw)[src])
                                   : ((const unsigned short*)Wraw)[src];
            if (e < 4) lo[e] = v; else hi[e - 4] = v;
        }
        *(us4g*)&Wf[(size_t)gid * 8]     = lo;
        *(us4g*)&Wf[(size_t)gid * 8 + 4] = hi;
    }
}

// --------------------------------------------------------------------------
// k_gemm1: h = X @ W per (b,h) + att epilogue + fragment-layout repack.
// grid 1024 (bh*32+it) x 256 (4 waves x 16 rows = 64 rows/block).
// Raw X read directly (fp32 -> bf16 in-register); Wf from global (L1/L2).
// hswz stored FP16; E/E5 fp16 table planes.
// --------------------------------------------------------------------------
constexpr int LDW = 264;
__global__ __launch_bounds__(256) void k_gemm1(const void* __restrict__ Xraw,
                                               const unsigned short* __restrict__ Wf,
                                               const void* __restrict__ aSraw,
                                               const void* __restrict__ aNraw,
                                               const float* __restrict__ Aw,
                                               unsigned short* __restrict__ hswz,
                                               float* __restrict__ att_s,
                                               unsigned short* __restrict__ Ef,
                                               unsigned short* __restrict__ E5f,
                                               unsigned int* __restrict__ maxn_enc) {
    int blk = blockIdx.x;
    int bh = blk >> 5, it = blk & 31;
    int b = bh >> 3, hh = bh & 7;
    int isf = gat_isf32(Aw);
#if defined(__gfx950__)
    __shared__ unsigned short CtT[64 * LDW];         // repack staging only
    int wave = threadIdx.x >> 6, lane = threadIdx.x & 63;
    int lrw = lane & 15, quad = lane >> 4;
    int row0 = it * 64 + wave * 16;
    const unsigned short* wfh = Wf + (size_t)hh * 16384 + lane * 8;
    size_t xbase = ((size_t)(b * GN) + row0 + lrw) * 256;
    f32x4g acc[4] = {};
#pragma unroll 2
    for (int kg = 0; kg < 8; kg++) {
        sh8 a;
        if (isf) {
            const float* xp = (const float*)Xraw + xbase + kg * 32 + quad * 8;
            f32x4g x0 = *(const f32x4g*)xp;
            f32x4g x1 = *(const f32x4g*)(xp + 4);
            unsigned int w0_, w1_, w2_, w3_;
            asm("v_cvt_pk_bf16_f32 %0, %1, %2" : "=v"(w0_) : "v"(x0[0]), "v"(x0[1]));
            asm("v_cvt_pk_bf16_f32 %0, %1, %2" : "=v"(w1_) : "v"(x0[2]), "v"(x0[3]));
            asm("v_cvt_pk_bf16_f32 %0, %1, %2" : "=v"(w2_) : "v"(x1[0]), "v"(x1[1]));
            asm("v_cvt_pk_bf16_f32 %0, %1, %2" : "=v"(w3_) : "v"(x1[2]), "v"(x1[3]));
            i32x4g aw = {(int)w0_, (int)w1_, (int)w2_, (int)w3_};
            a = *(sh8*)&aw;
        } else {
            a = *(const sh8*)((const unsigned short*)Xraw + xbase + kg * 32 + quad * 8);
        }
        const unsigned short* wp = wfh + kg * 2048;
        sh8 w0 = *(const sh8*)&wp[0];                // ct=0 (lane-linear 16B)
        sh8 w1 = *(const sh8*)&wp[512];              // ct=1
        sh8 w2 = *(const sh8*)&wp[1024];             // ct=2
        sh8 w3 = *(const sh8*)&wp[1536];             // ct=3
        acc[0] = __builtin_amdgcn_mfma_f32_16x16x32_bf16(a, w0, acc[0], 0, 0, 0);
        acc[1] = __builtin_amdgcn_mfma_f32_16x16x32_bf16(a, w1, acc[1], 0, 0, 0);
        acc[2] = __builtin_amdgcn_mfma_f32_16x16x32_bf16(a, w2, acc[2], 0, 0, 0);
        acc[3] = __builtin_amdgcn_mfma_f32_16x16x32_bf16(a, w3, acc[3], 0, 0, 0);
    }
    // ---- att epilogue (register-only): att_s, fp16 E/E5 planes, maxn ----
    float as_l[4], an_l[4];
#pragma unroll
    for (int ct = 0; ct < 4; ct++) {
        int col = hh * 64 + ct * 16 + lrw;
        as_l[ct] = isf ? ((const float*)aSraw)[col] : gat_bf2f(((const unsigned short*)aSraw)[col]);
        an_l[ct] = isf ? ((const float*)aNraw)[col] : gat_bf2f(((const unsigned short*)aNraw)[col]);
    }
    float wmax = -3e38f;
#pragma unroll
    for (int r = 0; r < 4; r++) {
        float ps = acc[0][r] * as_l[0] + acc[1][r] * as_l[1]
                 + acc[2][r] * as_l[2] + acc[3][r] * as_l[3];
        float pn = acc[0][r] * an_l[0] + acc[1][r] * an_l[1]
                 + acc[2][r] * an_l[2] + acc[3][r] * an_l[3];
        for (int off = 1; off < 16; off <<= 1) {
            ps += __shfl_xor(ps, off);
            pn += __shfl_xor(pn, off);
        }
        int row = row0 + quad * 4 + r;
        if (lrw == 0) {
            att_s[bh * GN + row] = ps;
            float pnc = fminf(pn, 10.0f);            // fp16 overflow guard
            Ef[bh * GN + row]  = gat_f2h(__expf(pnc));
            E5f[bh * GN + row] = gat_f2h(__expf(0.2f * pnc));
        }
        wmax = fmaxf(wmax, pn);
    }
    wmax = fmaxf(wmax, __shfl_xor(wmax, 16));
    wmax = fmaxf(wmax, __shfl_xor(wmax, 32));
    if (lane == 0) atomicMax(&maxn_enc[bh], gat_enc(wmax));
    // ---- repack: acc -> LDS CtT[o][nloc] -> hswz fragment layout (fp16) ----
#pragma unroll
    for (int ct = 0; ct < 4; ct++) {
        int o = ct * 16 + lrw;
        int nloc = wave * 16 + quad * 4;
        us4g v;
        v[0] = gat_f2h(acc[ct][0]);
        v[1] = gat_f2h(acc[ct][1]);
        v[2] = gat_f2h(acc[ct][2]);
        v[3] = gat_f2h(acc[ct][3]);
        *(us4g*)&CtT[o * LDW + nloc] = v;
    }
    __syncthreads();
    // 512 fragment-lane items (2 jc_loc x 4 ct x 64 lane), 2 per thread
#pragma unroll
    for (int k = 0; k < 2; k++) {
        int id = k * 256 + threadIdx.x;
        int ln = id & 63, t = id >> 6;               // t in [0,8)
        int jc_loc = t >> 2, ct = t & 3;
        int lrw2 = ln & 15, quad2 = ln >> 4;
        int o = ct * 16 + lrw2;
        int nloc = jc_loc * 32 + quad2 * 8;
        sh8 v = *(const sh8*)&CtT[o * LDW + nloc];
        size_t dst = ((((size_t)(bh * 64 + it * 2 + jc_loc)) * 4 + ct) * 64 + ln) * 8;
        *(sh8*)&hswz[dst] = v;
    }
#else
    // fallback: 64 rows/block, thread per row, scalar (correctness only)
    if (threadIdx.x < 64) {
        int row = it * 64 + threadIdx.x;
        float hrow[64];
        for (int col = 0; col < 64; col++) {
            float sacc = 0.f;
            for (int k = 0; k < 256; k++) {
                float xv = isf ? ((const float*)Xraw)[((size_t)(b * GN) + row) * 256 + k]
                               : gat_bf2f(((const unsigned short*)Xraw)[((size_t)(b * GN) + row) * 256 + k]);
                sacc += xv * gat_bf2f(Wf[gat_wf_idx(hh, k, col)]);
            }
            hrow[col] = sacc;
        }
        size_t base = (size_t)bh * 64 * GN;          // elems per bh slice = 64*2048
        for (int col = 0; col < 64; col++)
            hswz[base + gat_hswz_idx(col, row)] = gat_f2h(hrow[col]);
        float ps = 0.f, pn = 0.f;
        for (int col = 0; col < 64; col++) {
            float as = isf ? ((const float*)aSraw)[hh * 64 + col] : gat_bf2f(((const unsigned short*)aSraw)[hh * 64 + col]);
            float an = isf ? ((const float*)aNraw)[hh * 64 + col] : gat_bf2f(((const unsigned short*)aNraw)[hh * 64 + col]);
            ps += hrow[col] * as;
            pn += hrow[col] * an;
        }
        att_s[bh * GN + row] = ps;
        float pnc = fminf(pn, 10.0f);
        Ef[bh * GN + row]  = gat_f2h(__expf(pnc));
        E5f[bh * GN + row] = gat_f2h(__expf(0.2f * pnc));
        atomicMax(&maxn_enc[bh], gat_enc(pn));
    }
#endif
}

// --------------------------------------------------------------------------
// k_attn_av: out = relu( softmax(P) @ h ). grid 2048 (bh = blk&31 for XCD
// locality, it = blk>>5 -> 32 rows), 256 thr = 4 waves; wave w covers j in
// [w*512, +512) for the SAME 32 rows. Packed-fp16 P path:
//   per u32 (2 cols): pk_mul(k1,E) , pk_mul(k2,E5) , pk_max , AND M16
//   -> packed A-frag word; mfma_f32_16x16x32_f16.
// (max(k1*E, k2*E5) == exp(leakyrelu(z)-c): exp monotone, equal at z=0.)
// LDS end-reduction, no atomics. launch_bounds (256,4): VGPR cap 128 —
// cap 40 (min-waves 6) spilled the inner loop (r11, r15).
// --------------------------------------------------------------------------
__global__ __launch_bounds__(256, 4) void k_attn_av(const unsigned short* __restrict__ M16,
                                                    const unsigned short* __restrict__ hswz,
                                                    const float* __restrict__ att_s,
                                                    const unsigned short* __restrict__ Ef,
                                                    const unsigned short* __restrict__ E5f,
                                                    const unsigned int* __restrict__ maxn_enc,
                                                    const float* __restrict__ Aw,
                                                    void* __restrict__ outv) {
    int blk = blockIdx.x;
    int bh = blk & 31, it = blk >> 5;
    int b = bh >> 3, hh = bh & 7;
    int i0 = it * 32;
    int tid = threadIdx.x;
    int isf = gat_isf32(Aw);
    float maxn = gat_dec(maxn_enc[bh]);
#if defined(__gfx950__)
    int wave = tid >> 6, lane = tid & 63, lrw = lane & 15, quad = lane >> 4;
    int j0 = wave * 512;                             // this wave's j-quarter
    // per-wave fragment base: jc group wave*16, lane-linear
    const unsigned short* hs = hswz + ((size_t)(bh * 64) + wave * 16) * 2048 + lane * 8;
    const unsigned int* Eu  = (const unsigned int*)Ef  + (size_t)bh * 1024;
    const unsigned int* E5u = (const unsigned int*)E5f + (size_t)bh * 1024;
    unsigned int k1p[2], k2p[2];
    const unsigned int* mrow[2];
    for (int f = 0; f < 2; f++) {
        int row = i0 + f * 16 + lrw;
        float s = att_s[bh * GN + row];
        float z = s + maxn;
        float c = fmaxf(z, 0.2f * z);                // >= true row max
        unsigned int u1 = gat_f2h(__expf(s - c));
        unsigned int u2 = gat_f2h(__expf(0.2f * s - c));
        k1p[f] = u1 * 0x00010001u;                   // (k1,k1) fp16 pair
        k2p[f] = u2 * 0x00010001u;                   // (k2,k2) fp16 pair
        mrow[f] = (const unsigned int*)M16 + ((size_t)(b * GN) + row) * 1024;
    }
    f32x4g acc[2][4] = {};
    f32x4g accl[2] = {};
    hf8 ones;
#pragma unroll
    for (int e = 0; e < 8; e++) ones[e] = (_Float16)1.0f;

#pragma unroll 2
    for (int jc = 0; jc < 16; jc++) {
        int jh = ((j0 + jc * 32) >> 1) + quad * 4;   // u32 index (2 cols/u32)
        u32x4g Ep  = *(const u32x4g*)&Eu[jh];
        u32x4g E5p = *(const u32x4g*)&E5u[jh];
        u32x4g M0  = *(const u32x4g*)&mrow[0][jh];
        u32x4g M1  = *(const u32x4g*)&mrow[1][jh];
        const unsigned short* hp = hs + jc * 2048;
        hf8 b0 = *(const hf8*)&hp[0];                // ct=0 (lane-linear 16B)
        hf8 b1 = *(const hf8*)&hp[512];              // ct=1
        hf8 b2 = *(const hf8*)&hp[1024];             // ct=2
        hf8 b3 = *(const hf8*)&hp[1536];             // ct=3
        i32x4g f0, f1;
#pragma unroll
        for (int pp = 0; pp < 4; pp++) {
            unsigned int a0, a1, m0w, a2, a3, m1w;
            unsigned int ew = Ep[pp], e5w = E5p[pp];
            asm("v_pk_mul_f16 %0, %1, %2" : "=v"(a0)  : "v"(k1p[0]), "v"(ew));
            asm("v_pk_mul_f16 %0, %1, %2" : "=v"(a1)  : "v"(k2p[0]), "v"(e5w));
            asm("v_pk_max_f16 %0, %1, %2" : "=v"(m0w) : "v"(a0), "v"(a1));
            f0[pp] = (int)(m0w & M0[pp]);
            asm("v_pk_mul_f16 %0, %1, %2" : "=v"(a2)  : "v"(k1p[1]), "v"(ew));
            asm("v_pk_mul_f16 %0, %1, %2" : "=v"(a3)  : "v"(k2p[1]), "v"(e5w));
            asm("v_pk_max_f16 %0, %1, %2" : "=v"(m1w) : "v"(a2), "v"(a3));
            f1[pp] = (int)(m1w & M1[pp]);
        }
        hf8 af0 = *(hf8*)&f0;
        hf8 af1 = *(hf8*)&f1;
        acc[0][0] = __builtin_amdgcn_mfma_f32_16x16x32_f16(af0, b0, acc[0][0], 0, 0, 0);
        acc[1][0] = __builtin_amdgcn_mfma_f32_16x16x32_f16(af1, b0, acc[1][0], 0, 0, 0);
        acc[0][1] = __builtin_amdgcn_mfma_f32_16x16x32_f16(af0, b1, acc[0][1], 0, 0, 0);
        acc[1][1] = __builtin_amdgcn_mfma_f32_16x16x32_f16(af1, b1, acc[1][1], 0, 0, 0);
        acc[0][2] = __builtin_amdgcn_mfma_f32_16x16x32_f16(af0, b2, acc[0][2], 0, 0, 0);
        acc[1][2] = __builtin_amdgcn_mfma_f32_16x16x32_f16(af1, b2, acc[1][2], 0, 0, 0);
        acc[0][3] = __builtin_amdgcn_mfma_f32_16x16x32_f16(af0, b3, acc[0][3], 0, 0, 0);
        acc[1][3] = __builtin_amdgcn_mfma_f32_16x16x32_f16(af1, b3, acc[1][3], 0, 0, 0);
        accl[0] = __builtin_amdgcn_mfma_f32_16x16x32_f16(af0, ones, accl[0], 0, 0, 0);
        accl[1] = __builtin_amdgcn_mfma_f32_16x16x32_f16(af1, ones, accl[1], 0, 0, 0);
    }
    // ---- end-of-kernel reduction across the 4 j-quarter waves (LDS) ----
    __shared__ float lred[4 * 32];                   // [wave][row32]
    __shared__ float lsum[32];                       // 1/l per row
    __shared__ float red[4 * 2 * 16 * 17];           // [wave][f][r16][c16 pad17]
    if (lrw == 0) {
#pragma unroll
        for (int f = 0; f < 2; f++)
#pragma unroll
            for (int r = 0; r < 4; r++)
                lred[wave * 32 + f * 16 + quad * 4 + r] = accl[f][r];
    }
    __syncthreads();
    if (tid < 32)
        lsum[tid] = 1.0f / (lred[tid] + lred[32 + tid] + lred[64 + tid] + lred[96 + tid]);
    __syncthreads();
    for (int ct = 0; ct < 4; ct++) {
#pragma unroll
        for (int f = 0; f < 2; f++)
#pragma unroll
            for (int r = 0; r < 4; r++)
                red[wave * 544 + f * 272 + (quad * 4 + r) * 17 + lrw] = acc[f][ct][r];
        __syncthreads();
#pragma unroll
        for (int k = 0; k < 2; k++) {
            int pos = k * 256 + tid;                 // [0,512): f(1b) r16(4b) c16(4b)
            int f = pos >> 8, r16 = (pos >> 4) & 15, c16 = pos & 15;
            int bse = f * 272 + r16 * 17 + c16;
            float sum = red[bse] + red[bse + 544] + red[bse + 1088] + red[bse + 1632];
            float v = sum * lsum[f * 16 + r16];
            v = v > 0.f ? v : 0.f;
            int row = i0 + f * 16 + r16;
            size_t o = ((size_t)(b * GN) + row) * GHF + hh * 64 + ct * 16 + c16;
            if (isf) ((float*)outv)[o] = v;
            else     ((unsigned short*)outv)[o] = gat_f2bf(v);
        }
        __syncthreads();
    }
#else
    // correctness-only fallback: thread -> (row = tid>>3, 8-col eighth)
    int row = i0 + (tid >> 3), chh = (tid & 7) * 8;
    const unsigned short* hbb = hswz + (size_t)(bh * 64) * GN;  // per-bh slice
    const unsigned short* mr = M16 + ((size_t)(b * GN) + row) * GN;
    float s = att_s[bh * GN + row];
    float z = s + maxn;
    float c = fmaxf(z, 0.2f * z);
    float k1 = __expf(s - c), k2 = __expf(0.2f * s - c);
    float l = 0.f;
    float accS[8] = {};
    for (int j = 0; j < GN; j++) {
        if (!mr[j]) continue;
        float Ev  = gat_h2f(Ef[(size_t)bh * GN + j]);
        float E5v = gat_h2f(E5f[(size_t)bh * GN + j]);
        float p = fmaxf(k1 * Ev, k2 * E5v);
        p = gat_h2f(gat_f2h(p));                     // mirror fp16 rounding
        l += p;
        for (int cc = 0; cc < 8; cc++)
            accS[cc] += p * gat_h2f(hbb[gat_hswz_idx(chh + cc, j)]);
    }
    float li = 1.0f / l;
    for (int cc = 0; cc < 8; cc++) {
        float v = accS[cc] * li; v = v > 0.f ? v : 0.f;
        size_t oi = ((size_t)(b * GN) + row) * GHF + hh * 64 + chh + cc;
        if (isf) ((float*)outv)[oi] = v;
        else     ((unsigned short*)outv)[oi] = gat_f2bf(v);
    }
#endif
}

// --------------------------------------------------------------------------
extern "C" void kernel_launch(void* const* d_in, const int* in_sizes, int n_in,
                              void* d_out, int out_size, void* d_ws, size_t ws_size,
                              hipStream_t stream) {
    const void* X  = d_in[0];
    const void* A  = d_in[1];
    const void* W  = d_in[2];
    const void* aS = d_in[3];
    const void* aN = d_in[4];

    char* ws = (char*)d_ws;
    unsigned short* hswz = (unsigned short*)(ws + OFF_HS);
    float* att_s = (float*)(ws + OFF_ATTS);
    unsigned short* Ef  = (unsigned short*)(ws + OFF_EF);
    unsigned short* E5f = (unsigned short*)(ws + OFF_E5F);
    unsigned short* M16 = (unsigned short*)(ws + OFF_M16);
    unsigned int* maxn_enc = (unsigned int*)(ws + OFF_MAXN);
    unsigned short* Wf = (unsigned short*)(ws + OFF_WC);

    k_mask_conv<<<8256, 256, 0, stream>>>(A, W, M16, maxn_enc, Wf);
    k_gemm1<<<1024, 256, 0, stream>>>(X, Wf, aS, aN, (const float*)A,
                                      hswz, att_s, Ef, E5f, maxn_enc);
    k_attn_av<<<2048, 256, 0, stream>>>(M16, hswz, att_s, Ef, E5f, maxn_enc,
                                        (const float*)A, d_out);
}

// Round 5
// 211.654 us; speedup vs baseline: 1.0602x; 1.0602x over previous
//
#include <hip/hip_runtime.h>

// GraphAttention: B=4, N=2048, F=256, H=8, F_=64; out [B, N, 512].
// 3 dispatches:
//  k_mask_conv: A -> compact bitmask (byte stores, same bit image as u64
//               words LE) + init maxn; W -> bf16 MFMA B-fragment layout Wf.
//  k_gemm1    : h=X@W (MFMA, raw X converted bf16 in-register) + att
//               epilogue (att_s f32; E=exp(pn), E5=exp(0.2pn) fp16 planes;
//               per-bh max(att_n)) + LDS repack of h into MFMA fragment
//               layout hswz[bh][jc][ct][lane][8] (fp16).
//  k_attn_av  : fused masked softmax @ h. Packed-fp16 P path + COMPACT
//               bitmask expanded in-register:
//               per 2 cols: sbfe x2 -> halfword select mask;
//               pk_mul(k1,E), pk_mul(k2,E5), pk_max, AND -> A-frag word;
//               mfma_f32_16x16x32_f16. (max(k1*E,k2*E5) == exact leakyrelu
//               select: exp monotone, equal at z=0.)
// History: r9 global-atomic j-split -> 425MB HBM (never); r11/r15
// launch_bounds min-waves 6 -> VGPR cap 40 -> spills (KEEP CAP >= 128:
// 2nd arg <= 4 at 256 thr). r14 201us/attn 63; r16 203/57; r17 207/58
// (VALU-issue ~31us = 3x pure math; overhead); r18 224/72: pk-fp16 cut
// VALUBusy 53->17% BUT expanded M16 mask plane cost 141MB FETCH ->
// latency-bound. MASK MUST STAY BITMASK (L2-resident). This round:
// pk-fp16 + bitmask + in-reg sbfe expansion.
// Input dtype detected from A[0][0] (self-loop: fp32 word == 1.0f).

constexpr int GN  = 2048;
constexpr int GHF = 512;

using sh8    = __attribute__((ext_vector_type(8))) short;          // 8x16b
using hf8    = __attribute__((ext_vector_type(8))) _Float16;       // 8 fp16
using us4g   = __attribute__((ext_vector_type(4))) unsigned short;
using f32x4g = __attribute__((ext_vector_type(4))) float;
using u32x4g = __attribute__((ext_vector_type(4))) unsigned int;
using i32x4g = __attribute__((ext_vector_type(4))) int;

__device__ inline float gat_bf2f(unsigned short u) {
    union { unsigned int i; float f; } c; c.i = ((unsigned int)u) << 16; return c.f;
}
__device__ inline unsigned short gat_f2bf(float f) {
    union { float f; unsigned int i; } c; c.f = f;
    return (unsigned short)((c.i + 0x7fffu + ((c.i >> 16) & 1u)) >> 16); // RNE
}
__device__ inline unsigned short gat_f2h(float f) {
    _Float16 h = (_Float16)f;
    union { _Float16 h; unsigned short u; } c; c.h = h; return c.u;
}
__device__ inline float gat_h2f(unsigned short u) {
    union { _Float16 h; unsigned short u; } c; c.u = u; return (float)c.h;
}
__device__ inline int gat_isf32(const float* __restrict__ Aw) {
    float a = Aw[0];
    return (a == 0.0f) || (a == 1.0f);
}
__device__ inline unsigned int gat_enc(float f) {
    union { float f; unsigned int u; } c; c.f = f;
    return (c.u & 0x80000000u) ? ~c.u : (c.u | 0x80000000u);
}
__device__ inline float gat_dec(unsigned int e) {
    union { float f; unsigned int u; } c;
    c.u = (e & 0x80000000u) ? (e & 0x7fffffffu) : ~e;
    return c.f;
}
// fragment-layout accessor (scalar, fallback paths):
// h[o][j] of head-slice -> flat elem index in hswz (per-bh base excluded)
__device__ inline size_t gat_hswz_idx(int o, int j) {
    int jc = j >> 5, quad = (j >> 3) & 3, e = j & 7;
    int lane = quad * 16 + (o & 15);
    return (((size_t)(jc * 4 + (o >> 4))) * 64 + lane) * 8 + e;
}
// W fragment layout accessor: W[hh][k][col] -> flat index in Wf
__device__ inline size_t gat_wf_idx(int hh, int k, int col) {
    int kg = k >> 5, quad = (k >> 3) & 3, e = k & 7;
    int ct = col >> 4, lrw = col & 15;
    return ((((size_t)hh * 8 + kg) * 4 + ct) * 64 + (quad * 16 + lrw)) * 8 + e;
}

__global__ void GraphAttention_62981400429165_kernel() {}

// ---------------- workspace layout (bytes) ----------------
constexpr size_t OFF_HS   = 256;                       // hswz fp16      8 MB
constexpr size_t OFF_ATTS = OFF_HS   + 8388608;        // att_s f32    256 KB
constexpr size_t OFF_EF   = OFF_ATTS + 262144;         // E  fp16      128 KB
constexpr size_t OFF_E5F  = OFF_EF   + 131072;         // E5 fp16      128 KB
constexpr size_t OFF_MASK = OFF_E5F  + 131072;         // bitmask        2 MB
constexpr size_t OFF_MAXN = OFF_MASK + 2097152;        // 32 u32
constexpr size_t OFF_WC   = OFF_MAXN + 256;            // Wf bf16      256 KB

// --------------------------------------------------------------------------
// k_mask_conv: blocks 0..8191: A -> bitmask bytes (+block 0 inits maxn).
// 8192..8255: W -> Wf fragment layout (16B lane-linear stores).
// --------------------------------------------------------------------------
__global__ __launch_bounds__(256) void k_mask_conv(const void* __restrict__ Araw,
                                                   const void* __restrict__ Wraw,
                                                   unsigned long long* __restrict__ mask,
                                                   unsigned int* __restrict__ maxn_enc,
                                                   unsigned short* __restrict__ Wf) {
    int tid = threadIdx.x, blk = blockIdx.x;
    int isf = gat_isf32((const float*)Araw);
    if (blk < 8192) {
        if (blk == 0 && tid < 32) maxn_enc[tid] = 0u;
        size_t i8 = ((size_t)blk * 256 + tid) * 8;     // 8 A elems / thread
        unsigned int byte = 0;
        if (isf) {
            f32x4g v0 = *(const f32x4g*)((const float*)Araw + i8);
            f32x4g v1 = *(const f32x4g*)((const float*)Araw + i8 + 4);
#pragma unroll
            for (int e = 0; e < 4; e++) {
                byte |= (v0[e] != 0.0f ? 1u : 0u) << e;
                byte |= (v1[e] != 0.0f ? 1u : 0u) << (e + 4);
            }
        } else {
            u32x4g v = *(const u32x4g*)((const unsigned short*)Araw + i8);
#pragma unroll
            for (int w = 0; w < 4; w++) {
                byte |= ((v[w] & 0xffffu) != 0u ? 1u : 0u) << (2 * w);
                byte |= ((v[w] >> 16) != 0u ? 1u : 0u) << (2 * w + 1);
            }
        }
        ((unsigned char*)mask)[i8 >> 3] = (unsigned char)byte;
    } else {
        // W -> fragment layout. gid = hh*2048 + kg*256 + ct*64 + lane.
        int gid = (blk - 8192) * 256 + tid;          // [0, 16384)
        int lane = gid & 63, ct = (gid >> 6) & 3, kg = (gid >> 8) & 7, hh = gid >> 11;
        int quad = lane >> 4, lrw = lane & 15;
        int col = ct * 16 + lrw;
        us4g lo, hi;
#pragma unroll
        for (int e = 0; e < 8; e++) {
            int k = kg * 32 + quad * 8 + e;
            size_t src = (size_t)hh * 16384 + (size_t)k * 64 + col;
            unsigned short v = isf ? gat_f2bf(((const float*)Wraw)[src])
                                   : ((const unsigned short*)Wraw)[src];
            if (e < 4) lo[e] = v; else hi[e - 4] = v;
        }
        *(us4g*)&Wf[(size_t)gid * 8]     = lo;
        *(us4g*)&Wf[(size_t)gid * 8 + 4] = hi;
    }
}

// --------------------------------------------------------------------------
// k_gemm1: h = X @ W per (b,h) + att epilogue + fragment-layout repack.
// grid 1024 (bh*32+it) x 256 (4 waves x 16 rows = 64 rows/block).
// Raw X read directly (fp32 -> bf16 in-register); Wf from global (L1/L2).
// hswz stored FP16; E/E5 fp16 table planes.
// --------------------------------------------------------------------------
constexpr int LDW = 264;
__global__ __launch_bounds__(256) void k_gemm1(const void* __restrict__ Xraw,
                                               const unsigned short* __restrict__ Wf,
                                               const void* __restrict__ aSraw,
                                               const void* __restrict__ aNraw,
                                               const float* __restrict__ Aw,
                                               unsigned short* __restrict__ hswz,
                                               float* __restrict__ att_s,
                                               unsigned short* __restrict__ Ef,
                                               unsigned short* __restrict__ E5f,
                                               unsigned int* __restrict__ maxn_enc) {
    int blk = blockIdx.x;
    int bh = blk >> 5, it = blk & 31;
    int b = bh >> 3, hh = bh & 7;
    int isf = gat_isf32(Aw);
#if defined(__gfx950__)
    __shared__ unsigned short CtT[64 * LDW];         // repack staging only
    int wave = threadIdx.x >> 6, lane = threadIdx.x & 63;
    int lrw = lane & 15, quad = lane >> 4;
    int row0 = it * 64 + wave * 16;
    const unsigned short* wfh = Wf + (size_t)hh * 16384 + lane * 8;
    size_t xbase = ((size_t)(b * GN) + row0 + lrw) * 256;
    f32x4g acc[4] = {};
#pragma unroll 2
    for (int kg = 0; kg < 8; kg++) {
        sh8 a;
        if (isf) {
            const float* xp = (const float*)Xraw + xbase + kg * 32 + quad * 8;
            f32x4g x0 = *(const f32x4g*)xp;
            f32x4g x1 = *(const f32x4g*)(xp + 4);
            unsigned int w0_, w1_, w2_, w3_;
            asm("v_cvt_pk_bf16_f32 %0, %1, %2" : "=v"(w0_) : "v"(x0[0]), "v"(x0[1]));
            asm("v_cvt_pk_bf16_f32 %0, %1, %2" : "=v"(w1_) : "v"(x0[2]), "v"(x0[3]));
            asm("v_cvt_pk_bf16_f32 %0, %1, %2" : "=v"(w2_) : "v"(x1[0]), "v"(x1[1]));
            asm("v_cvt_pk_bf16_f32 %0, %1, %2" : "=v"(w3_) : "v"(x1[2]), "v"(x1[3]));
            i32x4g aw = {(int)w0_, (int)w1_, (int)w2_, (int)w3_};
            a = *(sh8*)&aw;
        } else {
            a = *(const sh8*)((const unsigned short*)Xraw + xbase + kg * 32 + quad * 8);
        }
        const unsigned short* wp = wfh + kg * 2048;
        sh8 w0 = *(const sh8*)&wp[0];                // ct=0 (lane-linear 16B)
        sh8 w1 = *(const sh8*)&wp[512];              // ct=1
        sh8 w2 = *(const sh8*)&wp[1024];             // ct=2
        sh8 w3 = *(const sh8*)&wp[1536];             // ct=3
        acc[0] = __builtin_amdgcn_mfma_f32_16x16x32_bf16(a, w0, acc[0], 0, 0, 0);
        acc[1] = __builtin_amdgcn_mfma_f32_16x16x32_bf16(a, w1, acc[1], 0, 0, 0);
        acc[2] = __builtin_amdgcn_mfma_f32_16x16x32_bf16(a, w2, acc[2], 0, 0, 0);
        acc[3] = __builtin_amdgcn_mfma_f32_16x16x32_bf16(a, w3, acc[3], 0, 0, 0);
    }
    // ---- att epilogue (register-only): att_s, fp16 E/E5 planes, maxn ----
    float as_l[4], an_l[4];
#pragma unroll
    for (int ct = 0; ct < 4; ct++) {
        int col = hh * 64 + ct * 16 + lrw;
        as_l[ct] = isf ? ((const float*)aSraw)[col] : gat_bf2f(((const unsigned short*)aSraw)[col]);
        an_l[ct] = isf ? ((const float*)aNraw)[col] : gat_bf2f(((const unsigned short*)aNraw)[col]);
    }
    float wmax = -3e38f;
#pragma unroll
    for (int r = 0; r < 4; r++) {
        float ps = acc[0][r] * as_l[0] + acc[1][r] * as_l[1]
                 + acc[2][r] * as_l[2] + acc[3][r] * as_l[3];
        float pn = acc[0][r] * an_l[0] + acc[1][r] * an_l[1]
                 + acc[2][r] * an_l[2] + acc[3][r] * an_l[3];
        for (int off = 1; off < 16; off <<= 1) {
            ps += __shfl_xor(ps, off);
            pn += __shfl_xor(pn, off);
        }
        int row = row0 + quad * 4 + r;
        if (lrw == 0) {
            att_s[bh * GN + row] = ps;
            float pnc = fminf(pn, 10.0f);            // fp16 overflow guard
            Ef[bh * GN + row]  = gat_f2h(__expf(pnc));
            E5f[bh * GN + row] = gat_f2h(__expf(0.2f * pnc));
        }
        wmax = fmaxf(wmax, pn);
    }
    wmax = fmaxf(wmax, __shfl_xor(wmax, 16));
    wmax = fmaxf(wmax, __shfl_xor(wmax, 32));
    if (lane == 0) atomicMax(&maxn_enc[bh], gat_enc(wmax));
    // ---- repack: acc -> LDS CtT[o][nloc] -> hswz fragment layout (fp16) ----
#pragma unroll
    for (int ct = 0; ct < 4; ct++) {
        int o = ct * 16 + lrw;
        int nloc = wave * 16 + quad * 4;
        us4g v;
        v[0] = gat_f2h(acc[ct][0]);
        v[1] = gat_f2h(acc[ct][1]);
        v[2] = gat_f2h(acc[ct][2]);
        v[3] = gat_f2h(acc[ct][3]);
        *(us4g*)&CtT[o * LDW + nloc] = v;
    }
    __syncthreads();
    // 512 fragment-lane items (2 jc_loc x 4 ct x 64 lane), 2 per thread
#pragma unroll
    for (int k = 0; k < 2; k++) {
        int id = k * 256 + threadIdx.x;
        int ln = id & 63, t = id >> 6;               // t in [0,8)
        int jc_loc = t >> 2, ct = t & 3;
        int lrw2 = ln & 15, quad2 = ln >> 4;
        int o = ct * 16 + lrw2;
        int nloc = jc_loc * 32 + quad2 * 8;
        sh8 v = *(const sh8*)&CtT[o * LDW + nloc];
        size_t dst = ((((size_t)(bh * 64 + it * 2 + jc_loc)) * 4 + ct) * 64 + ln) * 8;
        *(sh8*)&hswz[dst] = v;
    }
#else
    // fallback: 64 rows/block, thread per row, scalar (correctness only)
    if (threadIdx.x < 64) {
        int row = it * 64 + threadIdx.x;
        float hrow[64];
        for (int col = 0; col < 64; col++) {
            float sacc = 0.f;
            for (int k = 0; k < 256; k++) {
                float xv = isf ? ((const float*)Xraw)[((size_t)(b * GN) + row) * 256 + k]
                               : gat_bf2f(((const unsigned short*)Xraw)[((size_t)(b * GN) + row) * 256 + k]);
                sacc += xv * gat_bf2f(Wf[gat_wf_idx(hh, k, col)]);
            }
            hrow[col] = sacc;
        }
        size_t base = (size_t)bh * 64 * GN;          // elems per bh slice = 64*2048
        for (int col = 0; col < 64; col++)
            hswz[base + gat_hswz_idx(col, row)] = gat_f2h(hrow[col]);
        float ps = 0.f, pn = 0.f;
        for (int col = 0; col < 64; col++) {
            float as = isf ? ((const float*)aSraw)[hh * 64 + col] : gat_bf2f(((const unsigned short*)aSraw)[hh * 64 + col]);
            float an = isf ? ((const float*)aNraw)[hh * 64 + col] : gat_bf2f(((const unsigned short*)aNraw)[hh * 64 + col]);
            ps += hrow[col] * as;
            pn += hrow[col] * an;
        }
        att_s[bh * GN + row] = ps;
        float pnc = fminf(pn, 10.0f);
        Ef[bh * GN + row]  = gat_f2h(__expf(pnc));
        E5f[bh * GN + row] = gat_f2h(__expf(0.2f * pnc));
        atomicMax(&maxn_enc[bh], gat_enc(pn));
    }
#endif
}

// --------------------------------------------------------------------------
// k_attn_av: out = relu( softmax(P) @ h ). grid 2048 (bh = blk&31 for XCD
// locality, it = blk>>5 -> 32 rows), 256 thr = 4 waves; wave w covers j in
// [w*512, +512) for the SAME 32 rows. Packed-fp16 P from COMPACT bitmask:
//   per 2 cols: s0/s1 = sbfe(bits) -> (s0&0xFFFF)|(s1&0xFFFF0000) halfword
//   mask; pk_mul(k1,E), pk_mul(k2,E5), pk_max, AND -> A-frag word;
//   mfma_f32_16x16x32_f16.
// LDS end-reduction, no atomics. launch_bounds (256,4): VGPR cap 128 —
// cap 40 (min-waves 6) spilled the inner loop (r11, r15).
// --------------------------------------------------------------------------
__global__ __launch_bounds__(256, 4) void k_attn_av(const unsigned int* __restrict__ mask32,
                                                    const unsigned short* __restrict__ hswz,
                                                    const float* __restrict__ att_s,
                                                    const unsigned short* __restrict__ Ef,
                                                    const unsigned short* __restrict__ E5f,
                                                    const unsigned int* __restrict__ maxn_enc,
                                                    const float* __restrict__ Aw,
                                                    void* __restrict__ outv) {
    int blk = blockIdx.x;
    int bh = blk & 31, it = blk >> 5;
    int b = bh >> 3, hh = bh & 7;
    int i0 = it * 32;
    int tid = threadIdx.x;
    int isf = gat_isf32(Aw);
    float maxn = gat_dec(maxn_enc[bh]);
#if defined(__gfx950__)
    int wave = tid >> 6, lane = tid & 63, lrw = lane & 15, quad = lane >> 4;
    int kq = quad * 8;
    int j0 = wave * 512;                             // this wave's j-quarter
    // per-wave fragment base: jc group wave*16, lane-linear
    const unsigned short* hs = hswz + ((size_t)(bh * 64) + wave * 16) * 2048 + lane * 8;
    const unsigned int* Eu  = (const unsigned int*)Ef  + (size_t)bh * 1024;
    const unsigned int* E5u = (const unsigned int*)E5f + (size_t)bh * 1024;
    unsigned int k1p[2], k2p[2];
    const unsigned int* mrf[2];
    for (int f = 0; f < 2; f++) {
        int row = i0 + f * 16 + lrw;
        float s = att_s[bh * GN + row];
        float z = s + maxn;
        float c = fmaxf(z, 0.2f * z);                // >= true row max
        k1p[f] = (unsigned int)gat_f2h(__expf(s - c)) * 0x00010001u;
        k2p[f] = (unsigned int)gat_f2h(__expf(0.2f * s - c)) * 0x00010001u;
        mrf[f] = mask32 + ((size_t)(b * GN) + row) * 64 + wave * 16;
    }
    f32x4g acc[2][4] = {};
    f32x4g accl[2] = {};
    hf8 ones;
#pragma unroll
    for (int e = 0; e < 8; e++) ones[e] = (_Float16)1.0f;

#pragma unroll 1
    for (int jg = 0; jg < 4; jg++) {                 // 4 groups x 4 jc
        u32x4g m0 = *(const u32x4g*)&mrf[0][jg * 4];
        u32x4g m1 = *(const u32x4g*)&mrf[1][jg * 4];
#pragma unroll
        for (int sj = 0; sj < 4; sj++) {
            int jc = jg * 4 + sj;
            int jh = ((j0 + jc * 32) >> 1) + quad * 4;   // u32 idx (2 cols/u32)
            u32x4g Ep  = *(const u32x4g*)&Eu[jh];
            u32x4g E5p = *(const u32x4g*)&E5u[jh];
            const unsigned short* hp = hs + jc * 2048;
            hf8 b0 = *(const hf8*)&hp[0];            // ct=0 (lane-linear 16B)
            hf8 b1 = *(const hf8*)&hp[512];          // ct=1
            hf8 b2 = *(const hf8*)&hp[1024];         // ct=2
            hf8 b3 = *(const hf8*)&hp[1536];         // ct=3
            unsigned int wf0 = m0[sj] >> kq;
            unsigned int wf1 = m1[sj] >> kq;
            i32x4g f0, f1;
#pragma unroll
            for (int pp = 0; pp < 4; pp++) {
                unsigned int ew = Ep[pp], e5w = E5p[pp];
                unsigned int a0, a1, mx0, a2, a3, mx1;
                asm("v_pk_mul_f16 %0, %1, %2" : "=v"(a0)  : "v"(k1p[0]), "v"(ew));
                asm("v_pk_mul_f16 %0, %1, %2" : "=v"(a1)  : "v"(k2p[0]), "v"(e5w));
                asm("v_pk_max_f16 %0, %1, %2" : "=v"(mx0) : "v"(a0), "v"(a1));
                asm("v_pk_mul_f16 %0, %1, %2" : "=v"(a2)  : "v"(k1p[1]), "v"(ew));
                asm("v_pk_mul_f16 %0, %1, %2" : "=v"(a3)  : "v"(k2p[1]), "v"(e5w));
                asm("v_pk_max_f16 %0, %1, %2" : "=v"(mx1) : "v"(a2), "v"(a3));
                // bit (2pp) -> low halfword, bit (2pp+1) -> high halfword
                unsigned int s0 = (unsigned int)__builtin_amdgcn_sbfe((int)wf0, 2u * pp, 1u);
                unsigned int s1 = (unsigned int)__builtin_amdgcn_sbfe((int)wf0, 2u * pp + 1u, 1u);
                f0[pp] = (int)(mx0 & ((s0 & 0x0000FFFFu) | (s1 & 0xFFFF0000u)));
                unsigned int t0 = (unsigned int)__builtin_amdgcn_sbfe((int)wf1, 2u * pp, 1u);
                unsigned int t1 = (unsigned int)__builtin_amdgcn_sbfe((int)wf1, 2u * pp + 1u, 1u);
                f1[pp] = (int)(mx1 & ((t0 & 0x0000FFFFu) | (t1 & 0xFFFF0000u)));
            }
            hf8 af0 = *(hf8*)&f0;
            hf8 af1 = *(hf8*)&f1;
            acc[0][0] = __builtin_amdgcn_mfma_f32_16x16x32_f16(af0, b0, acc[0][0], 0, 0, 0);
            acc[1][0] = __builtin_amdgcn_mfma_f32_16x16x32_f16(af1, b0, acc[1][0], 0, 0, 0);
            acc[0][1] = __builtin_amdgcn_mfma_f32_16x16x32_f16(af0, b1, acc[0][1], 0, 0, 0);
            acc[1][1] = __builtin_amdgcn_mfma_f32_16x16x32_f16(af1, b1, acc[1][1], 0, 0, 0);
            acc[0][2] = __builtin_amdgcn_mfma_f32_16x16x32_f16(af0, b2, acc[0][2], 0, 0, 0);
            acc[1][2] = __builtin_amdgcn_mfma_f32_16x16x32_f16(af1, b2, acc[1][2], 0, 0, 0);
            acc[0][3] = __builtin_amdgcn_mfma_f32_16x16x32_f16(af0, b3, acc[0][3], 0, 0, 0);
            acc[1][3] = __builtin_amdgcn_mfma_f32_16x16x32_f16(af1, b3, acc[1][3], 0, 0, 0);
            accl[0] = __builtin_amdgcn_mfma_f32_16x16x32_f16(af0, ones, accl[0], 0, 0, 0);
            accl[1] = __builtin_amdgcn_mfma_f32_16x16x32_f16(af1, ones, accl[1], 0, 0, 0);
        }
    }
    // ---- end-of-kernel reduction across the 4 j-quarter waves (LDS) ----
    __shared__ float lred[4 * 32];                   // [wave][row32]
    __shared__ float lsum[32];                       // 1/l per row
    __shared__ float red[4 * 2 * 16 * 17];           // [wave][f][r16][c16 pad17]
    if (lrw == 0) {
#pragma unroll
        for (int f = 0; f < 2; f++)
#pragma unroll
            for (int r = 0; r < 4; r++)
                lred[wave * 32 + f * 16 + quad * 4 + r] = accl[f][r];
    }
    __syncthreads();
    if (tid < 32)
        lsum[tid] = 1.0f / (lred[tid] + lred[32 + tid] + lred[64 + tid] + lred[96 + tid]);
    __syncthreads();
    for (int ct = 0; ct < 4; ct++) {
#pragma unroll
        for (int f = 0; f < 2; f++)
#pragma unroll
            for (int r = 0; r < 4; r++)
                red[wave * 544 + f * 272 + (quad * 4 + r) * 17 + lrw] = acc[f][ct][r];
        __syncthreads();
#pragma unroll
        for (int k = 0; k < 2; k++) {
            int pos = k * 256 + tid;                 // [0,512): f(1b) r16(4b) c16(4b)
            int f = pos >> 8, r16 = (pos >> 4) & 15, c16 = pos & 15;
            int bse = f * 272 + r16 * 17 + c16;
            float sum = red[bse] + red[bse + 544] + red[bse + 1088] + red[bse + 1632];
            float v = sum * lsum[f * 16 + r16];
            v = v > 0.f ? v : 0.f;
            int row = i0 + f * 16 + r16;
            size_t o = ((size_t)(b * GN) + row) * GHF + hh * 64 + ct * 16 + c16;
            if (isf) ((float*)outv)[o] = v;
            else     ((unsigned short*)outv)[o] = gat_f2bf(v);
        }
        __syncthreads();
    }
#else
    // correctness-only fallback: thread -> (row = tid>>3, 8-col eighth)
    int row = i0 + (tid >> 3), chh = (tid & 7) * 8;
    const unsigned short* hbb = hswz + (size_t)(bh * 64) * GN;  // per-bh slice
    const unsigned int* mr = mask32 + ((size_t)(b * GN) + row) * 64;
    float s = att_s[bh * GN + row];
    float z = s + maxn;
    float c = fmaxf(z, 0.2f * z);
    unsigned short k1u = gat_f2h(__expf(s - c));
    unsigned short k2u = gat_f2h(__expf(0.2f * s - c));
    float l = 0.f;
    float accS[8] = {};
    for (int j = 0; j < GN; j++) {
        if (!((mr[j >> 5] >> (j & 31)) & 1u)) continue;
        // mirror fp16 pk math: mul in fp16, max in fp16
        float a0 = gat_h2f(gat_f2h(gat_h2f(k1u) * gat_h2f(Ef[(size_t)bh * GN + j])));
        float a1 = gat_h2f(gat_f2h(gat_h2f(k2u) * gat_h2f(E5f[(size_t)bh * GN + j])));
        float p = fmaxf(a0, a1);
        l += p;
        for (int cc = 0; cc < 8; cc++)
            accS[cc] += p * gat_h2f(hbb[gat_hswz_idx(chh + cc, j)]);
    }
    float li = 1.0f / l;
    for (int cc = 0; cc < 8; cc++) {
        float v = accS[cc] * li; v = v > 0.f ? v : 0.f;
        size_t oi = ((size_t)(b * GN) + row) * GHF + hh * 64 + chh + cc;
        if (isf) ((float*)outv)[oi] = v;
        else     ((unsigned short*)outv)[oi] = gat_f2bf(v);
    }
#endif
}

// --------------------------------------------------------------------------
extern "C" void kernel_launch(void* const* d_in, const int* in_sizes, int n_in,
                              void* d_out, int out_size, void* d_ws, size_t ws_size,
                              hipStream_t stream) {
    const void* X  = d_in[0];
    const void* A  = d_in[1];
    const void* W  = d_in[2];
    const void* aS = d_in[3];
    const void* aN = d_in[4];

    char* ws = (char*)d_ws;
    unsigned short* hswz = (unsigned short*)(ws + OFF_HS);
    float* att_s = (float*)(ws + OFF_ATTS);
    unsigned short* Ef  = (unsigned short*)(ws + OFF_EF);
    unsigned short* E5f = (unsigned short*)(ws + OFF_E5F);
    unsigned long long* mask = (unsigned long long*)(ws + OFF_MASK);
    unsigned int* maxn_enc = (unsigned int*)(ws + OFF_MAXN);
    unsigned short* Wf = (unsigned short*)(ws + OFF_WC);

    k_mask_conv<<<8256, 256, 0, stream>>>(A, W, mask, maxn_enc, Wf);
    k_gemm1<<<1024, 256, 0, stream>>>(X, Wf, aS, aN, (const float*)A,
                                      hswz, att_s, Ef, E5f, maxn_enc);
    k_attn_av<<<2048, 256, 0, stream>>>((const unsigned int*)mask, hswz,
                                        att_s, Ef, E5f, maxn_enc,
                                        (const float*)A, d_out);
}

// Round 6
// 200.489 us; speedup vs baseline: 1.1192x; 1.0557x over previous
//
#include <hip/hip_runtime.h>

// GraphAttention: B=4, N=2048, F=256, H=8, F_=64; out [B, N, 512].
// 3 dispatches:
//  k_mask_conv: A -> compact bitmask (byte stores, same bit image as u64
//               words LE) + init maxn; W -> bf16 MFMA B-fragment layout Wf.
//  k_gemm1    : h=X@W (MFMA, raw X converted bf16 in-register) + att
//               epilogue (att_s f32; E=exp(pn), E5=exp(0.2pn) fp16 planes;
//               per-bh max(att_n)) + LDS repack of h into MFMA fragment
//               layout hswz[bh][jc][ct][lane][8] (fp16).
//  k_attn_av  : fused masked softmax @ h. 64 ROWS/BLOCK (4 row-frags),
//               grid 1024, 4 waves x j-quarter. Packed-fp16 P from compact
//               bitmask: per 2 cols: sbfe x2 -> halfword mask; pk_mul(k1,E),
//               pk_mul(k2,E5), pk_max, AND -> A-frag word; mfma f16.
//               Same 4 b-frag loads feed 20 MFMAs (was 10): 2x arithmetic
//               intensity per load, hswz L2 traffic 512->256 MB.
// History: r9 global-atomic j-split -> 425MB HBM (never); r11/r15
// launch_bounds VGPR cap 40 -> spills (KEEP CAP >= 128). r14 201us/attn 63;
// r16 203/57; r17 207/58; r18 224/72 (expanded mask 141MB FETCH - never);
// r19 212/58: VALUBusy 53->32% but time FLAT => attn is NOT VALU-bound;
// it's load-latency-bound on hswz b-frag stream (6 VMEM per 10 MFMA,
// 512MB L2 re-read). This round: 64 rows/block, 20 MFMA per 6 VMEM.
// Input dtype detected from A[0][0] (self-loop: fp32 word == 1.0f).

constexpr int GN  = 2048;
constexpr int GHF = 512;

using sh8    = __attribute__((ext_vector_type(8))) short;          // 8x16b
using hf8    = __attribute__((ext_vector_type(8))) _Float16;       // 8 fp16
using us4g   = __attribute__((ext_vector_type(4))) unsigned short;
using f32x4g = __attribute__((ext_vector_type(4))) float;
using u32x4g = __attribute__((ext_vector_type(4))) unsigned int;
using i32x4g = __attribute__((ext_vector_type(4))) int;

__device__ inline float gat_bf2f(unsigned short u) {
    union { unsigned int i; float f; } c; c.i = ((unsigned int)u) << 16; return c.f;
}
__device__ inline unsigned short gat_f2bf(float f) {
    union { float f; unsigned int i; } c; c.f = f;
    return (unsigned short)((c.i + 0x7fffu + ((c.i >> 16) & 1u)) >> 16); // RNE
}
__device__ inline unsigned short gat_f2h(float f) {
    _Float16 h = (_Float16)f;
    union { _Float16 h; unsigned short u; } c; c.h = h; return c.u;
}
__device__ inline float gat_h2f(unsigned short u) {
    union { _Float16 h; unsigned short u; } c; c.u = u; return (float)c.h;
}
__device__ inline int gat_isf32(const float* __restrict__ Aw) {
    float a = Aw[0];
    return (a == 0.0f) || (a == 1.0f);
}
__device__ inline unsigned int gat_enc(float f) {
    union { float f; unsigned int u; } c; c.f = f;
    return (c.u & 0x80000000u) ? ~c.u : (c.u | 0x80000000u);
}
__device__ inline float gat_dec(unsigned int e) {
    union { float f; unsigned int u; } c;
    c.u = (e & 0x80000000u) ? (e & 0x7fffffffu) : ~e;
    return c.f;
}
// fragment-layout accessor (scalar, fallback paths):
// h[o][j] of head-slice -> flat elem index in hswz (per-bh base excluded)
__device__ inline size_t gat_hswz_idx(int o, int j) {
    int jc = j >> 5, quad = (j >> 3) & 3, e = j & 7;
    int lane = quad * 16 + (o & 15);
    return (((size_t)(jc * 4 + (o >> 4))) * 64 + lane) * 8 + e;
}
// W fragment layout accessor: W[hh][k][col] -> flat index in Wf
__device__ inline size_t gat_wf_idx(int hh, int k, int col) {
    int kg = k >> 5, quad = (k >> 3) & 3, e = k & 7;
    int ct = col >> 4, lrw = col & 15;
    return ((((size_t)hh * 8 + kg) * 4 + ct) * 64 + (quad * 16 + lrw)) * 8 + e;
}

__global__ void GraphAttention_62981400429165_kernel() {}

// ---------------- workspace layout (bytes) ----------------
constexpr size_t OFF_HS   = 256;                       // hswz fp16      8 MB
constexpr size_t OFF_ATTS = OFF_HS   + 8388608;        // att_s f32    256 KB
constexpr size_t OFF_EF   = OFF_ATTS + 262144;         // E  fp16      128 KB
constexpr size_t OFF_E5F  = OFF_EF   + 131072;         // E5 fp16      128 KB
constexpr size_t OFF_MASK = OFF_E5F  + 131072;         // bitmask        2 MB
constexpr size_t OFF_MAXN = OFF_MASK + 2097152;        // 32 u32
constexpr size_t OFF_WC   = OFF_MAXN + 256;            // Wf bf16      256 KB

// --------------------------------------------------------------------------
// k_mask_conv: blocks 0..8191: A -> bitmask bytes (+block 0 inits maxn).
// 8192..8255: W -> Wf fragment layout (16B lane-linear stores).
// --------------------------------------------------------------------------
__global__ __launch_bounds__(256) void k_mask_conv(const void* __restrict__ Araw,
                                                   const void* __restrict__ Wraw,
                                                   unsigned long long* __restrict__ mask,
                                                   unsigned int* __restrict__ maxn_enc,
                                                   unsigned short* __restrict__ Wf) {
    int tid = threadIdx.x, blk = blockIdx.x;
    int isf = gat_isf32((const float*)Araw);
    if (blk < 8192) {
        if (blk == 0 && tid < 32) maxn_enc[tid] = 0u;
        size_t i8 = ((size_t)blk * 256 + tid) * 8;     // 8 A elems / thread
        unsigned int byte = 0;
        if (isf) {
            f32x4g v0 = *(const f32x4g*)((const float*)Araw + i8);
            f32x4g v1 = *(const f32x4g*)((const float*)Araw + i8 + 4);
#pragma unroll
            for (int e = 0; e < 4; e++) {
                byte |= (v0[e] != 0.0f ? 1u : 0u) << e;
                byte |= (v1[e] != 0.0f ? 1u : 0u) << (e + 4);
            }
        } else {
            u32x4g v = *(const u32x4g*)((const unsigned short*)Araw + i8);
#pragma unroll
            for (int w = 0; w < 4; w++) {
                byte |= ((v[w] & 0xffffu) != 0u ? 1u : 0u) << (2 * w);
                byte |= ((v[w] >> 16) != 0u ? 1u : 0u) << (2 * w + 1);
            }
        }
        ((unsigned char*)mask)[i8 >> 3] = (unsigned char)byte;
    } else {
        // W -> fragment layout. gid = hh*2048 + kg*256 + ct*64 + lane.
        int gid = (blk - 8192) * 256 + tid;          // [0, 16384)
        int lane = gid & 63, ct = (gid >> 6) & 3, kg = (gid >> 8) & 7, hh = gid >> 11;
        int quad = lane >> 4, lrw = lane & 15;
        int col = ct * 16 + lrw;
        us4g lo, hi;
#pragma unroll
        for (int e = 0; e < 8; e++) {
            int k = kg * 32 + quad * 8 + e;
            size_t src = (size_t)hh * 16384 + (size_t)k * 64 + col;
            unsigned short v = isf ? gat_f2bf(((const float*)Wraw)[src])
                                   : ((const unsigned short*)Wraw)[src];
            if (e < 4) lo[e] = v; else hi[e - 4] = v;
        }
        *(us4g*)&Wf[(size_t)gid * 8]     = lo;
        *(us4g*)&Wf[(size_t)gid * 8 + 4] = hi;
    }
}

// --------------------------------------------------------------------------
// k_gemm1: h = X @ W per (b,h) + att epilogue + fragment-layout repack.
// grid 1024 (bh*32+it) x 256 (4 waves x 16 rows = 64 rows/block).
// Raw X read directly (fp32 -> bf16 in-register); Wf from global (L1/L2).
// hswz stored FP16; E/E5 fp16 table planes.
// --------------------------------------------------------------------------
constexpr int LDW = 264;
__global__ __launch_bounds__(256) void k_gemm1(const void* __restrict__ Xraw,
                                               const unsigned short* __restrict__ Wf,
                                               const void* __restrict__ aSraw,
                                               const void* __restrict__ aNraw,
                                               const float* __restrict__ Aw,
                                               unsigned short* __restrict__ hswz,
                                               float* __restrict__ att_s,
                                               unsigned short* __restrict__ Ef,
                                               unsigned short* __restrict__ E5f,
                                               unsigned int* __restrict__ maxn_enc) {
    int blk = blockIdx.x;
    int bh = blk >> 5, it = blk & 31;
    int b = bh >> 3, hh = bh & 7;
    int isf = gat_isf32(Aw);
#if defined(__gfx950__)
    __shared__ unsigned short CtT[64 * LDW];         // repack staging only
    int wave = threadIdx.x >> 6, lane = threadIdx.x & 63;
    int lrw = lane & 15, quad = lane >> 4;
    int row0 = it * 64 + wave * 16;
    const unsigned short* wfh = Wf + (size_t)hh * 16384 + lane * 8;
    size_t xbase = ((size_t)(b * GN) + row0 + lrw) * 256;
    f32x4g acc[4] = {};
#pragma unroll 2
    for (int kg = 0; kg < 8; kg++) {
        sh8 a;
        if (isf) {
            const float* xp = (const float*)Xraw + xbase + kg * 32 + quad * 8;
            f32x4g x0 = *(const f32x4g*)xp;
            f32x4g x1 = *(const f32x4g*)(xp + 4);
            unsigned int w0_, w1_, w2_, w3_;
            asm("v_cvt_pk_bf16_f32 %0, %1, %2" : "=v"(w0_) : "v"(x0[0]), "v"(x0[1]));
            asm("v_cvt_pk_bf16_f32 %0, %1, %2" : "=v"(w1_) : "v"(x0[2]), "v"(x0[3]));
            asm("v_cvt_pk_bf16_f32 %0, %1, %2" : "=v"(w2_) : "v"(x1[0]), "v"(x1[1]));
            asm("v_cvt_pk_bf16_f32 %0, %1, %2" : "=v"(w3_) : "v"(x1[2]), "v"(x1[3]));
            i32x4g aw = {(int)w0_, (int)w1_, (int)w2_, (int)w3_};
            a = *(sh8*)&aw;
        } else {
            a = *(const sh8*)((const unsigned short*)Xraw + xbase + kg * 32 + quad * 8);
        }
        const unsigned short* wp = wfh + kg * 2048;
        sh8 w0 = *(const sh8*)&wp[0];                // ct=0 (lane-linear 16B)
        sh8 w1 = *(const sh8*)&wp[512];              // ct=1
        sh8 w2 = *(const sh8*)&wp[1024];             // ct=2
        sh8 w3 = *(const sh8*)&wp[1536];             // ct=3
        acc[0] = __builtin_amdgcn_mfma_f32_16x16x32_bf16(a, w0, acc[0], 0, 0, 0);
        acc[1] = __builtin_amdgcn_mfma_f32_16x16x32_bf16(a, w1, acc[1], 0, 0, 0);
        acc[2] = __builtin_amdgcn_mfma_f32_16x16x32_bf16(a, w2, acc[2], 0, 0, 0);
        acc[3] = __builtin_amdgcn_mfma_f32_16x16x32_bf16(a, w3, acc[3], 0, 0, 0);
    }
    // ---- att epilogue (register-only): att_s, fp16 E/E5 planes, maxn ----
    float as_l[4], an_l[4];
#pragma unroll
    for (int ct = 0; ct < 4; ct++) {
        int col = hh * 64 + ct * 16 + lrw;
        as_l[ct] = isf ? ((const float*)aSraw)[col] : gat_bf2f(((const unsigned short*)aSraw)[col]);
        an_l[ct] = isf ? ((const float*)aNraw)[col] : gat_bf2f(((const unsigned short*)aNraw)[col]);
    }
    float wmax = -3e38f;
#pragma unroll
    for (int r = 0; r < 4; r++) {
        float ps = acc[0][r] * as_l[0] + acc[1][r] * as_l[1]
                 + acc[2][r] * as_l[2] + acc[3][r] * as_l[3];
        float pn = acc[0][r] * an_l[0] + acc[1][r] * an_l[1]
                 + acc[2][r] * an_l[2] + acc[3][r] * an_l[3];
        for (int off = 1; off < 16; off <<= 1) {
            ps += __shfl_xor(ps, off);
            pn += __shfl_xor(pn, off);
        }
        int row = row0 + quad * 4 + r;
        if (lrw == 0) {
            att_s[bh * GN + row] = ps;
            float pnc = fminf(pn, 10.0f);            // fp16 overflow guard
            Ef[bh * GN + row]  = gat_f2h(__expf(pnc));
            E5f[bh * GN + row] = gat_f2h(__expf(0.2f * pnc));
        }
        wmax = fmaxf(wmax, pn);
    }
    wmax = fmaxf(wmax, __shfl_xor(wmax, 16));
    wmax = fmaxf(wmax, __shfl_xor(wmax, 32));
    if (lane == 0) atomicMax(&maxn_enc[bh], gat_enc(wmax));
    // ---- repack: acc -> LDS CtT[o][nloc] -> hswz fragment layout (fp16) ----
#pragma unroll
    for (int ct = 0; ct < 4; ct++) {
        int o = ct * 16 + lrw;
        int nloc = wave * 16 + quad * 4;
        us4g v;
        v[0] = gat_f2h(acc[ct][0]);
        v[1] = gat_f2h(acc[ct][1]);
        v[2] = gat_f2h(acc[ct][2]);
        v[3] = gat_f2h(acc[ct][3]);
        *(us4g*)&CtT[o * LDW + nloc] = v;
    }
    __syncthreads();
    // 512 fragment-lane items (2 jc_loc x 4 ct x 64 lane), 2 per thread
#pragma unroll
    for (int k = 0; k < 2; k++) {
        int id = k * 256 + threadIdx.x;
        int ln = id & 63, t = id >> 6;               // t in [0,8)
        int jc_loc = t >> 2, ct = t & 3;
        int lrw2 = ln & 15, quad2 = ln >> 4;
        int o = ct * 16 + lrw2;
        int nloc = jc_loc * 32 + quad2 * 8;
        sh8 v = *(const sh8*)&CtT[o * LDW + nloc];
        size_t dst = ((((size_t)(bh * 64 + it * 2 + jc_loc)) * 4 + ct) * 64 + ln) * 8;
        *(sh8*)&hswz[dst] = v;
    }
#else
    // fallback: 64 rows/block, thread per row, scalar (correctness only)
    if (threadIdx.x < 64) {
        int row = it * 64 + threadIdx.x;
        float hrow[64];
        for (int col = 0; col < 64; col++) {
            float sacc = 0.f;
            for (int k = 0; k < 256; k++) {
                float xv = isf ? ((const float*)Xraw)[((size_t)(b * GN) + row) * 256 + k]
                               : gat_bf2f(((const unsigned short*)Xraw)[((size_t)(b * GN) + row) * 256 + k]);
                sacc += xv * gat_bf2f(Wf[gat_wf_idx(hh, k, col)]);
            }
            hrow[col] = sacc;
        }
        size_t base = (size_t)bh * 64 * GN;          // elems per bh slice = 64*2048
        for (int col = 0; col < 64; col++)
            hswz[base + gat_hswz_idx(col, row)] = gat_f2h(hrow[col]);
        float ps = 0.f, pn = 0.f;
        for (int col = 0; col < 64; col++) {
            float as = isf ? ((const float*)aSraw)[hh * 64 + col] : gat_bf2f(((const unsigned short*)aSraw)[hh * 64 + col]);
            float an = isf ? ((const float*)aNraw)[hh * 64 + col] : gat_bf2f(((const unsigned short*)aNraw)[hh * 64 + col]);
            ps += hrow[col] * as;
            pn += hrow[col] * an;
        }
        att_s[bh * GN + row] = ps;
        float pnc = fminf(pn, 10.0f);
        Ef[bh * GN + row]  = gat_f2h(__expf(pnc));
        E5f[bh * GN + row] = gat_f2h(__expf(0.2f * pnc));
        atomicMax(&maxn_enc[bh], gat_enc(pn));
    }
#endif
}

// --------------------------------------------------------------------------
// k_attn_av: out = relu( softmax(P) @ h ). grid 1024 (bh = blk&31 keeps the
// 64 it-blocks of one bh on ONE XCD: blk%8 == bh%8 -> hswz slice L2-resident;
// it = blk>>5 -> 64 rows), 256 thr = 4 waves; wave w covers j in [w*512,
// +512) for the SAME 64 rows (4 row-frags f=0..3). Per sj-tile: 6 VMEM
// (E,E5,b0..b3) feed 20 MFMAs (4f x 4ct + 4 accl) — 2x intensity vs r19.
// launch_bounds (256,2): VGPR cap 256 — NO spill risk (r11/r15: cap < live
// set spills catastrophically; low occupancy is the milder failure).
// --------------------------------------------------------------------------
__global__ __launch_bounds__(256, 2) void k_attn_av(const unsigned int* __restrict__ mask32,
                                                    const unsigned short* __restrict__ hswz,
                                                    const float* __restrict__ att_s,
                                                    const unsigned short* __restrict__ Ef,
                                                    const unsigned short* __restrict__ E5f,
                                                    const unsigned int* __restrict__ maxn_enc,
                                                    const float* __restrict__ Aw,
                                                    void* __restrict__ outv) {
    int blk = blockIdx.x;
    int bh = blk & 31, it = blk >> 5;
    int b = bh >> 3, hh = bh & 7;
    int i0 = it * 64;
    int tid = threadIdx.x;
    int isf = gat_isf32(Aw);
    float maxn = gat_dec(maxn_enc[bh]);
#if defined(__gfx950__)
    int wave = tid >> 6, lane = tid & 63, lrw = lane & 15, quad = lane >> 4;
    int kq = quad * 8;
    int j0 = wave * 512;                             // this wave's j-quarter
    // per-wave fragment base: jc group wave*16, lane-linear
    const unsigned short* hs = hswz + ((size_t)(bh * 64) + wave * 16) * 2048 + lane * 8;
    const unsigned int* Eu  = (const unsigned int*)Ef  + (size_t)bh * 1024;
    const unsigned int* E5u = (const unsigned int*)E5f + (size_t)bh * 1024;
    unsigned int k1p[4], k2p[4];
    const unsigned int* mrf[4];
#pragma unroll
    for (int f = 0; f < 4; f++) {
        int row = i0 + f * 16 + lrw;
        float s = att_s[bh * GN + row];
        float z = s + maxn;
        float c = fmaxf(z, 0.2f * z);                // >= true row max
        k1p[f] = (unsigned int)gat_f2h(__expf(s - c)) * 0x00010001u;
        k2p[f] = (unsigned int)gat_f2h(__expf(0.2f * s - c)) * 0x00010001u;
        mrf[f] = mask32 + ((size_t)(b * GN) + row) * 64 + wave * 16;
    }
    f32x4g acc[4][4] = {};
    f32x4g accl[4] = {};
    hf8 ones;
#pragma unroll
    for (int e = 0; e < 8; e++) ones[e] = (_Float16)1.0f;

#pragma unroll 1
    for (int jg = 0; jg < 4; jg++) {                 // 4 groups x 4 jc
        u32x4g m0 = *(const u32x4g*)&mrf[0][jg * 4];
        u32x4g m1 = *(const u32x4g*)&mrf[1][jg * 4];
        u32x4g m2 = *(const u32x4g*)&mrf[2][jg * 4];
        u32x4g m3 = *(const u32x4g*)&mrf[3][jg * 4];
#pragma unroll
        for (int sj = 0; sj < 4; sj++) {
            int jc = jg * 4 + sj;
            int jh = ((j0 + jc * 32) >> 1) + quad * 4;   // u32 idx (2 cols/u32)
            u32x4g Ep  = *(const u32x4g*)&Eu[jh];
            u32x4g E5p = *(const u32x4g*)&E5u[jh];
            const unsigned short* hp = hs + jc * 2048;
            hf8 b0 = *(const hf8*)&hp[0];            // ct=0 (lane-linear 16B)
            hf8 b1 = *(const hf8*)&hp[512];          // ct=1
            hf8 b2 = *(const hf8*)&hp[1024];         // ct=2
            hf8 b3 = *(const hf8*)&hp[1536];         // ct=3
            unsigned int wfm[4];
            wfm[0] = m0[sj] >> kq;
            wfm[1] = m1[sj] >> kq;
            wfm[2] = m2[sj] >> kq;
            wfm[3] = m3[sj] >> kq;
#pragma unroll
            for (int f = 0; f < 4; f++) {
                i32x4g fa;
#pragma unroll
                for (int pp = 0; pp < 4; pp++) {
                    unsigned int ew = Ep[pp], e5w = E5p[pp];
                    unsigned int a0, a1, mx;
                    asm("v_pk_mul_f16 %0, %1, %2" : "=v"(a0) : "v"(k1p[f]), "v"(ew));
                    asm("v_pk_mul_f16 %0, %1, %2" : "=v"(a1) : "v"(k2p[f]), "v"(e5w));
                    asm("v_pk_max_f16 %0, %1, %2" : "=v"(mx) : "v"(a0), "v"(a1));
                    // bit (2pp) -> low halfword, bit (2pp+1) -> high halfword
                    unsigned int s0 = (unsigned int)__builtin_amdgcn_sbfe((int)wfm[f], 2u * pp, 1u);
                    unsigned int s1 = (unsigned int)__builtin_amdgcn_sbfe((int)wfm[f], 2u * pp + 1u, 1u);
                    fa[pp] = (int)(mx & ((s0 & 0x0000FFFFu) | (s1 & 0xFFFF0000u)));
                }
                hf8 af = *(hf8*)&fa;
                acc[f][0] = __builtin_amdgcn_mfma_f32_16x16x32_f16(af, b0, acc[f][0], 0, 0, 0);
                acc[f][1] = __builtin_amdgcn_mfma_f32_16x16x32_f16(af, b1, acc[f][1], 0, 0, 0);
                acc[f][2] = __builtin_amdgcn_mfma_f32_16x16x32_f16(af, b2, acc[f][2], 0, 0, 0);
                acc[f][3] = __builtin_amdgcn_mfma_f32_16x16x32_f16(af, b3, acc[f][3], 0, 0, 0);
                accl[f]   = __builtin_amdgcn_mfma_f32_16x16x32_f16(af, ones, accl[f], 0, 0, 0);
            }
        }
    }
    // ---- end-of-kernel reduction across the 4 j-quarter waves (LDS) ----
    __shared__ float lred[4 * 64];                   // [wave][row64]
    __shared__ float lsum[64];                       // 1/l per row
    __shared__ float red[4 * 4 * 16 * 17];           // [wave][f][r16][c16 pad17]
    if (lrw == 0) {
#pragma unroll
        for (int f = 0; f < 4; f++)
#pragma unroll
            for (int r = 0; r < 4; r++)
                lred[wave * 64 + f * 16 + quad * 4 + r] = accl[f][r];
    }
    __syncthreads();
    if (tid < 64)
        lsum[tid] = 1.0f / (lred[tid] + lred[64 + tid] + lred[128 + tid] + lred[192 + tid]);
    __syncthreads();
    for (int ct = 0; ct < 4; ct++) {
#pragma unroll
        for (int f = 0; f < 4; f++)
#pragma unroll
            for (int r = 0; r < 4; r++)
                red[((wave * 4 + f) * 16 + quad * 4 + r) * 17 + lrw] = acc[f][ct][r];
        __syncthreads();
#pragma unroll
        for (int k = 0; k < 4; k++) {
            int pos = k * 256 + tid;                 // [0,1024): f(2b) r16(4b) c16(4b)
            int f = pos >> 8, r16 = (pos >> 4) & 15, c16 = pos & 15;
            int bse = (f * 16 + r16) * 17 + c16;
            float sum = red[bse] + red[bse + 1088] + red[bse + 2176] + red[bse + 3264];
            float v = sum * lsum[f * 16 + r16];
            v = v > 0.f ? v : 0.f;
            int row = i0 + f * 16 + r16;
            size_t o = ((size_t)(b * GN) + row) * GHF + hh * 64 + ct * 16 + c16;
            if (isf) ((float*)outv)[o] = v;
            else     ((unsigned short*)outv)[o] = gat_f2bf(v);
        }
        __syncthreads();
    }
#else
    // correctness-only fallback: thread -> (row = i0 + tid>>2, 16-col quarter)
    int row = i0 + (tid >> 2), chh = (tid & 3) * 16;
    const unsigned short* hbb = hswz + (size_t)(bh * 64) * GN;  // per-bh slice
    const unsigned int* mr = mask32 + ((size_t)(b * GN) + row) * 64;
    float s = att_s[bh * GN + row];
    float z = s + maxn;
    float c = fmaxf(z, 0.2f * z);
    unsigned short k1u = gat_f2h(__expf(s - c));
    unsigned short k2u = gat_f2h(__expf(0.2f * s - c));
    float l = 0.f;
    float accS[16] = {};
    for (int j = 0; j < GN; j++) {
        if (!((mr[j >> 5] >> (j & 31)) & 1u)) continue;
        // mirror fp16 pk math: mul in fp16, max in fp16
        float a0 = gat_h2f(gat_f2h(gat_h2f(k1u) * gat_h2f(Ef[(size_t)bh * GN + j])));
        float a1 = gat_h2f(gat_f2h(gat_h2f(k2u) * gat_h2f(E5f[(size_t)bh * GN + j])));
        float p = fmaxf(a0, a1);
        l += p;
        for (int cc = 0; cc < 16; cc++)
            accS[cc] += p * gat_h2f(hbb[gat_hswz_idx(chh + cc, j)]);
    }
    float li = 1.0f / l;
    for (int cc = 0; cc < 16; cc++) {
        float v = accS[cc] * li; v = v > 0.f ? v : 0.f;
        size_t oi = ((size_t)(b * GN) + row) * GHF + hh * 64 + chh + cc;
        if (isf) ((float*)outv)[oi] = v;
        else     ((unsigned short*)outv)[oi] = gat_f2bf(v);
    }
#endif
}

// --------------------------------------------------------------------------
extern "C" void kernel_launch(void* const* d_in, const int* in_sizes, int n_in,
                              void* d_out, int out_size, void* d_ws, size_t ws_size,
                              hipStream_t stream) {
    const void* X  = d_in[0];
    const void* A  = d_in[1];
    const void* W  = d_in[2];
    const void* aS = d_in[3];
    const void* aN = d_in[4];

    char* ws = (char*)d_ws;
    unsigned short* hswz = (unsigned short*)(ws + OFF_HS);
    float* att_s = (float*)(ws + OFF_ATTS);
    unsigned short* Ef  = (unsigned short*)(ws + OFF_EF);
    unsigned short* E5f = (unsigned short*)(ws + OFF_E5F);
    unsigned long long* mask = (unsigned long long*)(ws + OFF_MASK);
    unsigned int* maxn_enc = (unsigned int*)(ws + OFF_MAXN);
    unsigned short* Wf = (unsigned short*)(ws + OFF_WC);

    k_mask_conv<<<8256, 256, 0, stream>>>(A, W, mask, maxn_enc, Wf);
    k_gemm1<<<1024, 256, 0, stream>>>(X, Wf, aS, aN, (const float*)A,
                                      hswz, att_s, Ef, E5f, maxn_enc);
    k_attn_av<<<1024, 256, 0, stream>>>((const unsigned int*)mask, hswz,
                                        att_s, Ef, E5f, maxn_enc,
                                        (const float*)A, d_out);
}

// Round 9
// 176.486 us; speedup vs baseline: 1.2714x; 1.1360x over previous
//
#include <hip/hip_runtime.h>

// GraphAttention: B=4, N=2048, F=256, H=8, F_=64; out [B, N, 512].
// 2 dispatches (testing the per-dispatch-floor hypothesis from r20):
//  k_gemm1 (grid 9216):
//    blocks 0..1023  : h=X@W per (b,h), 64 rows/block. W self-converted
//                      raw->bf16 MFMA B-fragment layout in LDS (per-wave
//                      coalesced row loads). + att epilogue (att_s;
//                      E=exp(pn), E5=exp(0.2pn) fp16 planes; per-wave maxn
//                      store — NO atomics) + LDS repack of h into fragment
//                      layout hswz[bh][jc][ct][lane][8] (fp16).
//    blocks 1024..9215: A -> compact bitmask (consumed only by k_attn_av,
//                      next dispatch — no intra-dispatch dependency).
//  k_attn_av (grid 1024): fused masked softmax @ h, 64 rows/block, 4 waves
//    x j-quarter; packed-fp16 P from bitmask (sbfe halfword expand, pk_mul
//    x2, pk_max, AND); mfma f16; 20 MFMA per 6 VMEM. maxn from maxn_arr
//    (2 loads + 6 shfl). LDS end-reduction. IDENTICAL to r20's attn (ran OK).
// History: r9 global-atomic j-split -> 425MB HBM (never); r11/r15 VGPR cap
// 40 -> spills (KEEP CAP >= 128). r14 201/attn 63; r16 203/57; r17 207/58;
// r18 224/72 (expanded mask 141MB FETCH - never); r19 212/58 (VALU cut,
// time flat -> not VALU-bound); r20 200.5: attn < 54.6, gemm1 VISIBLE at
// 55us with ALL counters idle (Mfma 1.3%, VALU 3.4%, HBM 3.2%) => ~55us/
// dispatch floor suspected. r21: compile error (helper decl order). r22:
// fixed, container failed twice (audited clean: bounds/alignment/races all
// verified — attributing to infra). r23: resubmit, cast cleanup only.
// Input dtype detected from A[0][0] (self-loop: fp32 word == 1.0f).

constexpr int GN  = 2048;
constexpr int GHF = 512;

using sh8    = __attribute__((ext_vector_type(8))) short;          // 8x16b
using hf8    = __attribute__((ext_vector_type(8))) _Float16;       // 8 fp16
using us4g   = __attribute__((ext_vector_type(4))) unsigned short;
using f32x4g = __attribute__((ext_vector_type(4))) float;
using u32x4g = __attribute__((ext_vector_type(4))) unsigned int;
using i32x4g = __attribute__((ext_vector_type(4))) int;

__device__ inline float gat_bf2f(unsigned short u) {
    union { unsigned int i; float f; } c; c.i = ((unsigned int)u) << 16; return c.f;
}
__device__ inline unsigned short gat_f2bf(float f) {
    union { float f; unsigned int i; } c; c.f = f;
    return (unsigned short)((c.i + 0x7fffu + ((c.i >> 16) & 1u)) >> 16); // RNE
}
__device__ inline unsigned short gat_f2h(float f) {
    _Float16 h = (_Float16)f;
    union { _Float16 h; unsigned short u; } c; c.h = h; return c.u;
}
__device__ inline float gat_h2f(unsigned short u) {
    union { _Float16 h; unsigned short u; } c; c.u = u; return (float)c.h;
}
__device__ inline int gat_isf32(const float* __restrict__ Aw) {
    float a = Aw[0];
    return (a == 0.0f) || (a == 1.0f);
}
// fragment-layout accessor (scalar, fallback paths):
// h[o][j] of head-slice -> flat elem index in hswz (per-bh base excluded)
__device__ inline size_t gat_hswz_idx(int o, int j) {
    int jc = j >> 5, quad = (j >> 3) & 3, e = j & 7;
    int lane = quad * 16 + (o & 15);
    return (((size_t)(jc * 4 + (o >> 4))) * 64 + lane) * 8 + e;
}

__global__ void GraphAttention_62981400429165_kernel() {}

// ---------------- workspace layout (bytes) ----------------
constexpr size_t OFF_HS   = 256;                       // hswz fp16      8 MB
constexpr size_t OFF_ATTS = OFF_HS   + 8388608;        // att_s f32    256 KB
constexpr size_t OFF_EF   = OFF_ATTS + 262144;         // E  fp16      128 KB
constexpr size_t OFF_E5F  = OFF_EF   + 131072;         // E5 fp16      128 KB
constexpr size_t OFF_MASK = OFF_E5F  + 131072;         // bitmask        2 MB
constexpr size_t OFF_MAXN = OFF_MASK + 2097152;        // 32bh x 32it x 4w f32

// --------------------------------------------------------------------------
// k_gemm1: blocks 0..1023: h = X @ W per (b,h) + att epilogue + repack.
//          blocks 1024..9215: A -> bitmask bytes.
// gemm part: 256 thr = 4 waves x 16 rows = 64 rows/block. W fragments built
// in LDS by the block itself; X raw (fp32->bf16 in-register).
// --------------------------------------------------------------------------
constexpr int LDW = 264;
__global__ __launch_bounds__(256) void k_gemm1(const float* __restrict__ Xraw,
                                               const float* __restrict__ Wraw,
                                               const float* __restrict__ aSraw,
                                               const float* __restrict__ aNraw,
                                               const float* __restrict__ Aw,
                                               unsigned short* __restrict__ hswz,
                                               float* __restrict__ att_s,
                                               unsigned short* __restrict__ Ef,
                                               unsigned short* __restrict__ E5f,
                                               float* __restrict__ maxn_arr,
                                               unsigned char* __restrict__ maskB) {
    int tid = threadIdx.x, blk = blockIdx.x;
    int isf = gat_isf32(Aw);
    if (blk >= 1024) {
        // ---- A -> bitmask (8 elems/thread, 32B/lane reads, byte store) ----
        size_t i8 = ((size_t)(blk - 1024) * 256 + tid) * 8;
        unsigned int byte = 0;
        if (isf) {
            f32x4g v0 = *(const f32x4g*)(Aw + i8);
            f32x4g v1 = *(const f32x4g*)(Aw + i8 + 4);
#pragma unroll
            for (int e = 0; e < 4; e++) {
                byte |= (v0[e] != 0.0f ? 1u : 0u) << e;
                byte |= (v1[e] != 0.0f ? 1u : 0u) << (e + 4);
            }
        } else {
            const unsigned short* Au = (const unsigned short*)Aw;
            u32x4g v = *(const u32x4g*)(Au + i8);
#pragma unroll
            for (int w = 0; w < 4; w++) {
                byte |= ((v[w] & 0xffffu) != 0u ? 1u : 0u) << (2 * w);
                byte |= ((v[w] >> 16) != 0u ? 1u : 0u) << (2 * w + 1);
            }
        }
        maskB[i8 >> 3] = (unsigned char)byte;
        return;
    }
    int bh = blk >> 5, it = blk & 31;
    int b = bh >> 3, hh = bh & 7;
#if defined(__gfx950__)
    __shared__ unsigned short SH[64 * LDW];          // W frags, then CtT repack
    int wave = tid >> 6, lane = tid & 63;
    int lrw = lane & 15, quad = lane >> 4;
    // ---- W -> fragment layout in LDS (wave w: k rows w*64..+63) ----
    // frag offset(k, col) = (k>>5)*2048 + (col>>4)*512 + ((k>>3)&3)*128
    //                     + (col&15)*8 + (k&7); col = lane (coalesced row).
    for (int i = 0; i < 64; i++) {
        int k = wave * 64 + i;
        unsigned short v;
        if (isf) v = gat_f2bf(Wraw[(size_t)hh * 16384 + k * 64 + lane]);
        else     v = ((const unsigned short*)Wraw)[(size_t)hh * 16384 + k * 64 + lane];
        SH[(k >> 5) * 2048 + (lane >> 4) * 512 + ((k >> 3) & 3) * 128
           + (lane & 15) * 8 + (k & 7)] = v;
    }
    __syncthreads();
    int row0 = it * 64 + wave * 16;
    size_t xbase = ((size_t)(b * GN) + row0 + lrw) * 256;
    f32x4g acc[4] = {};
#pragma unroll 2
    for (int kg = 0; kg < 8; kg++) {
        sh8 a;
        if (isf) {
            const float* xp = Xraw + xbase + kg * 32 + quad * 8;
            f32x4g x0 = *(const f32x4g*)xp;
            f32x4g x1 = *(const f32x4g*)(xp + 4);
            unsigned int w0_, w1_, w2_, w3_;
            asm("v_cvt_pk_bf16_f32 %0, %1, %2" : "=v"(w0_) : "v"(x0[0]), "v"(x0[1]));
            asm("v_cvt_pk_bf16_f32 %0, %1, %2" : "=v"(w1_) : "v"(x0[2]), "v"(x0[3]));
            asm("v_cvt_pk_bf16_f32 %0, %1, %2" : "=v"(w2_) : "v"(x1[0]), "v"(x1[1]));
            asm("v_cvt_pk_bf16_f32 %0, %1, %2" : "=v"(w3_) : "v"(x1[2]), "v"(x1[3]));
            i32x4g aw = {(int)w0_, (int)w1_, (int)w2_, (int)w3_};
            a = *(sh8*)&aw;
        } else {
            a = *(const sh8*)((const unsigned short*)Xraw + xbase + kg * 32 + quad * 8);
        }
        const unsigned short* wp = &SH[kg * 2048 + lane * 8];
        sh8 w0 = *(const sh8*)&wp[0];                // ct=0 (lane-linear 16B)
        sh8 w1 = *(const sh8*)&wp[512];              // ct=1
        sh8 w2 = *(const sh8*)&wp[1024];             // ct=2
        sh8 w3 = *(const sh8*)&wp[1536];             // ct=3
        acc[0] = __builtin_amdgcn_mfma_f32_16x16x32_bf16(a, w0, acc[0], 0, 0, 0);
        acc[1] = __builtin_amdgcn_mfma_f32_16x16x32_bf16(a, w1, acc[1], 0, 0, 0);
        acc[2] = __builtin_amdgcn_mfma_f32_16x16x32_bf16(a, w2, acc[2], 0, 0, 0);
        acc[3] = __builtin_amdgcn_mfma_f32_16x16x32_bf16(a, w3, acc[3], 0, 0, 0);
    }
    // ---- att epilogue (register-only): att_s, fp16 E/E5, per-wave maxn ----
    float as_l[4], an_l[4];
#pragma unroll
    for (int ct = 0; ct < 4; ct++) {
        int col = hh * 64 + ct * 16 + lrw;
        as_l[ct] = isf ? aSraw[col] : gat_bf2f(((const unsigned short*)aSraw)[col]);
        an_l[ct] = isf ? aNraw[col] : gat_bf2f(((const unsigned short*)aNraw)[col]);
    }
    float wmax = -3e38f;
#pragma unroll
    for (int r = 0; r < 4; r++) {
        float ps = acc[0][r] * as_l[0] + acc[1][r] * as_l[1]
                 + acc[2][r] * as_l[2] + acc[3][r] * as_l[3];
        float pn = acc[0][r] * an_l[0] + acc[1][r] * an_l[1]
                 + acc[2][r] * an_l[2] + acc[3][r] * an_l[3];
        for (int off = 1; off < 16; off <<= 1) {
            ps += __shfl_xor(ps, off);
            pn += __shfl_xor(pn, off);
        }
        int row = row0 + quad * 4 + r;
        if (lrw == 0) {
            att_s[bh * GN + row] = ps;
            float pnc = fminf(pn, 10.0f);            // fp16 overflow guard
            Ef[bh * GN + row]  = gat_f2h(__expf(pnc));
            E5f[bh * GN + row] = gat_f2h(__expf(0.2f * pnc));
        }
        wmax = fmaxf(wmax, pn);
    }
    wmax = fmaxf(wmax, __shfl_xor(wmax, 16));
    wmax = fmaxf(wmax, __shfl_xor(wmax, 32));
    if (lane == 0) maxn_arr[((bh << 5) | it) * 4 + wave] = wmax;  // race-free
    // ---- repack: acc -> LDS CtT[o][nloc] -> hswz fragment layout (fp16) ----
    __syncthreads();                                  // W-frag reads done; reuse SH
    unsigned short* CtT = SH;                         // [o][nloc], stride LDW
#pragma unroll
    for (int ct = 0; ct < 4; ct++) {
        int o = ct * 16 + lrw;
        int nloc = wave * 16 + quad * 4;
        us4g v;
        v[0] = gat_f2h(acc[ct][0]);
        v[1] = gat_f2h(acc[ct][1]);
        v[2] = gat_f2h(acc[ct][2]);
        v[3] = gat_f2h(acc[ct][3]);
        *(us4g*)&CtT[o * LDW + nloc] = v;
    }
    __syncthreads();
    // 512 fragment-lane items (2 jc_loc x 4 ct x 64 lane), 2 per thread
#pragma unroll
    for (int k = 0; k < 2; k++) {
        int id = k * 256 + tid;
        int ln = id & 63, t = id >> 6;               // t in [0,8)
        int jc_loc = t >> 2, ct = t & 3;
        int lrw2 = ln & 15, quad2 = ln >> 4;
        int o = ct * 16 + lrw2;
        int nloc = jc_loc * 32 + quad2 * 8;
        sh8 v = *(const sh8*)&CtT[o * LDW + nloc];
        size_t dst = ((((size_t)(bh * 64 + it * 2 + jc_loc)) * 4 + ct) * 64 + ln) * 8;
        *(sh8*)&hswz[dst] = v;
    }
#else
    // fallback: 64 rows/block, thread per row, scalar (correctness only)
    __shared__ float fm[256];
    float pn_keep = -3e38f;
    if (tid < 64) {
        int row = it * 64 + tid;
        float hrow[64];
        for (int col = 0; col < 64; col++) {
            float sacc = 0.f;
            for (int k = 0; k < 256; k++) {
                float xv = isf ? Xraw[((size_t)(b * GN) + row) * 256 + k]
                               : gat_bf2f(((const unsigned short*)Xraw)[((size_t)(b * GN) + row) * 256 + k]);
                unsigned short wu = isf ? gat_f2bf(Wraw[(size_t)hh * 16384 + k * 64 + col])
                                        : ((const unsigned short*)Wraw)[(size_t)hh * 16384 + k * 64 + col];
                sacc += xv * gat_bf2f(wu);
            }
            hrow[col] = sacc;
        }
        size_t base = (size_t)bh * 64 * GN;          // elems per bh slice = 64*2048
        for (int col = 0; col < 64; col++)
            hswz[base + gat_hswz_idx(col, row)] = gat_f2h(hrow[col]);
        float ps = 0.f, pn = 0.f;
        for (int col = 0; col < 64; col++) {
            float as = isf ? aSraw[hh * 64 + col] : gat_bf2f(((const unsigned short*)aSraw)[hh * 64 + col]);
            float an = isf ? aNraw[hh * 64 + col] : gat_bf2f(((const unsigned short*)aNraw)[hh * 64 + col]);
            ps += hrow[col] * as;
            pn += hrow[col] * an;
        }
        att_s[bh * GN + row] = ps;
        float pnc = fminf(pn, 10.0f);
        Ef[bh * GN + row]  = gat_f2h(__expf(pnc));
        E5f[bh * GN + row] = gat_f2h(__expf(0.2f * pnc));
        pn_keep = pn;
    }
    fm[tid] = pn_keep;
    __syncthreads();
    if (tid == 0) {
        float m = -3e38f;
        for (int q = 0; q < 256; q++) m = fmaxf(m, fm[q]);
        for (int w = 0; w < 4; w++) maxn_arr[((bh << 5) | it) * 4 + w] = m;
    }
#endif
}

// --------------------------------------------------------------------------
// k_attn_av: out = relu( softmax(P) @ h ). grid 1024 (bh = blk&31, it =
// blk>>5 -> 64 rows), 256 thr = 4 waves; wave w covers j in [w*512, +512)
// for the SAME 64 rows (4 row-frags). Per sj-tile: 6 VMEM feed 20 MFMAs.
// maxn reduced from maxn_arr (2 loads + 6 shfl). launch_bounds (256,2):
// VGPR cap 256 — NO spill risk (r11/r15).
// --------------------------------------------------------------------------
__global__ __launch_bounds__(256, 2) void k_attn_av(const unsigned int* __restrict__ mask32,
                                                    const unsigned short* __restrict__ hswz,
                                                    const float* __restrict__ att_s,
                                                    const unsigned short* __restrict__ Ef,
                                                    const unsigned short* __restrict__ E5f,
                                                    const float* __restrict__ maxn_arr,
                                                    const float* __restrict__ Aw,
                                                    void* __restrict__ outv) {
    int blk = blockIdx.x;
    int bh = blk & 31, it = blk >> 5;
    int b = bh >> 3, hh = bh & 7;
    int i0 = it * 64;
    int tid = threadIdx.x;
    int isf = gat_isf32(Aw);
#if defined(__gfx950__)
    int wave = tid >> 6, lane = tid & 63, lrw = lane & 15, quad = lane >> 4;
    int kq = quad * 8;
    int j0 = wave * 512;                             // this wave's j-quarter
    // global max(att_n) for bh: reduce the 128 per-wave partials
    float mxl = -3e38f;
    for (int q = lane; q < 128; q += 64) mxl = fmaxf(mxl, maxn_arr[bh * 128 + q]);
#pragma unroll
    for (int off = 1; off < 64; off <<= 1) mxl = fmaxf(mxl, __shfl_xor(mxl, off));
    float maxn = mxl;
    // per-wave fragment base: jc group wave*16, lane-linear
    const unsigned short* hs = hswz + ((size_t)(bh * 64) + wave * 16) * 2048 + lane * 8;
    const unsigned int* Eu  = (const unsigned int*)Ef  + (size_t)bh * 1024;
    const unsigned int* E5u = (const unsigned int*)E5f + (size_t)bh * 1024;
    unsigned int k1p[4], k2p[4];
    const unsigned int* mrf[4];
#pragma unroll
    for (int f = 0; f < 4; f++) {
        int row = i0 + f * 16 + lrw;
        float s = att_s[bh * GN + row];
        float z = s + maxn;
        float c = fmaxf(z, 0.2f * z);                // >= true row max
        k1p[f] = (unsigned int)gat_f2h(__expf(s - c)) * 0x00010001u;
        k2p[f] = (unsigned int)gat_f2h(__expf(0.2f * s - c)) * 0x00010001u;
        mrf[f] = mask32 + ((size_t)(b * GN) + row) * 64 + wave * 16;
    }
    f32x4g acc[4][4] = {};
    f32x4g accl[4] = {};
    hf8 ones;
#pragma unroll
    for (int e = 0; e < 8; e++) ones[e] = (_Float16)1.0f;

#pragma unroll 1
    for (int jg = 0; jg < 4; jg++) {                 // 4 groups x 4 jc
        u32x4g m0 = *(const u32x4g*)&mrf[0][jg * 4];
        u32x4g m1 = *(const u32x4g*)&mrf[1][jg * 4];
        u32x4g m2 = *(const u32x4g*)&mrf[2][jg * 4];
        u32x4g m3 = *(const u32x4g*)&mrf[3][jg * 4];
#pragma unroll
        for (int sj = 0; sj < 4; sj++) {
            int jc = jg * 4 + sj;
            int jh = ((j0 + jc * 32) >> 1) + quad * 4;   // u32 idx (2 cols/u32)
            u32x4g Ep  = *(const u32x4g*)&Eu[jh];
            u32x4g E5p = *(const u32x4g*)&E5u[jh];
            const unsigned short* hp = hs + jc * 2048;
            hf8 b0 = *(const hf8*)&hp[0];            // ct=0 (lane-linear 16B)
            hf8 b1 = *(const hf8*)&hp[512];          // ct=1
            hf8 b2 = *(const hf8*)&hp[1024];         // ct=2
            hf8 b3 = *(const hf8*)&hp[1536];         // ct=3
            unsigned int wfm[4];
            wfm[0] = m0[sj] >> kq;
            wfm[1] = m1[sj] >> kq;
            wfm[2] = m2[sj] >> kq;
            wfm[3] = m3[sj] >> kq;
#pragma unroll
            for (int f = 0; f < 4; f++) {
                i32x4g fa;
#pragma unroll
                for (int pp = 0; pp < 4; pp++) {
                    unsigned int ew = Ep[pp], e5w = E5p[pp];
                    unsigned int a0, a1, mx;
                    asm("v_pk_mul_f16 %0, %1, %2" : "=v"(a0) : "v"(k1p[f]), "v"(ew));
                    asm("v_pk_mul_f16 %0, %1, %2" : "=v"(a1) : "v"(k2p[f]), "v"(e5w));
                    asm("v_pk_max_f16 %0, %1, %2" : "=v"(mx) : "v"(a0), "v"(a1));
                    // bit (2pp) -> low halfword, bit (2pp+1) -> high halfword
                    unsigned int s0 = (unsigned int)__builtin_amdgcn_sbfe((int)wfm[f], 2u * pp, 1u);
                    unsigned int s1 = (unsigned int)__builtin_amdgcn_sbfe((int)wfm[f], 2u * pp + 1u, 1u);
                    fa[pp] = (int)(mx & ((s0 & 0x0000FFFFu) | (s1 & 0xFFFF0000u)));
                }
                hf8 af = *(hf8*)&fa;
                acc[f][0] = __builtin_amdgcn_mfma_f32_16x16x32_f16(af, b0, acc[f][0], 0, 0, 0);
                acc[f][1] = __builtin_amdgcn_mfma_f32_16x16x32_f16(af, b1, acc[f][1], 0, 0, 0);
                acc[f][2] = __builtin_amdgcn_mfma_f32_16x16x32_f16(af, b2, acc[f][2], 0, 0, 0);
                acc[f][3] = __builtin_amdgcn_mfma_f32_16x16x32_f16(af, b3, acc[f][3], 0, 0, 0);
                accl[f]   = __builtin_amdgcn_mfma_f32_16x16x32_f16(af, ones, accl[f], 0, 0, 0);
            }
        }
    }
    // ---- end-of-kernel reduction across the 4 j-quarter waves (LDS) ----
    __shared__ float lred[4 * 64];                   // [wave][row64]
    __shared__ float lsum[64];                       // 1/l per row
    __shared__ float red[4 * 4 * 16 * 17];           // [wave][f][r16][c16 pad17]
    if (lrw == 0) {
#pragma unroll
        for (int f = 0; f < 4; f++)
#pragma unroll
            for (int r = 0; r < 4; r++)
                lred[wave * 64 + f * 16 + quad * 4 + r] = accl[f][r];
    }
    __syncthreads();
    if (tid < 64)
        lsum[tid] = 1.0f / (lred[tid] + lred[64 + tid] + lred[128 + tid] + lred[192 + tid]);
    __syncthreads();
    for (int ct = 0; ct < 4; ct++) {
#pragma unroll
        for (int f = 0; f < 4; f++)
#pragma unroll
            for (int r = 0; r < 4; r++)
                red[((wave * 4 + f) * 16 + quad * 4 + r) * 17 + lrw] = acc[f][ct][r];
        __syncthreads();
#pragma unroll
        for (int k = 0; k < 4; k++) {
            int pos = k * 256 + tid;                 // [0,1024): f(2b) r16(4b) c16(4b)
            int f = pos >> 8, r16 = (pos >> 4) & 15, c16 = pos & 15;
            int bse = (f * 16 + r16) * 17 + c16;
            float sum = red[bse] + red[bse + 1088] + red[bse + 2176] + red[bse + 3264];
            float v = sum * lsum[f * 16 + r16];
            v = v > 0.f ? v : 0.f;
            int row = i0 + f * 16 + r16;
            size_t o = ((size_t)(b * GN) + row) * GHF + hh * 64 + ct * 16 + c16;
            if (isf) ((float*)outv)[o] = v;
            else     ((unsigned short*)outv)[o] = gat_f2bf(v);
        }
        __syncthreads();
    }
#else
    // correctness-only fallback: thread -> (row = i0 + tid>>2, 16-col quarter)
    float maxn = -3e38f;
    for (int q = 0; q < 128; q++) maxn = fmaxf(maxn, maxn_arr[bh * 128 + q]);
    int row = i0 + (tid >> 2), chh = (tid & 3) * 16;
    const unsigned short* hbb = hswz + (size_t)(bh * 64) * GN;  // per-bh slice
    const unsigned int* mr = mask32 + ((size_t)(b * GN) + row) * 64;
    float s = att_s[bh * GN + row];
    float z = s + maxn;
    float c = fmaxf(z, 0.2f * z);
    unsigned short k1u = gat_f2h(__expf(s - c));
    unsigned short k2u = gat_f2h(__expf(0.2f * s - c));
    float l = 0.f;
    float accS[16] = {};
    for (int j = 0; j < GN; j++) {
        if (!((mr[j >> 5] >> (j & 31)) & 1u)) continue;
        // mirror fp16 pk math: mul in fp16, max in fp16
        float a0 = gat_h2f(gat_f2h(gat_h2f(k1u) * gat_h2f(Ef[(size_t)bh * GN + j])));
        float a1 = gat_h2f(gat_f2h(gat_h2f(k2u) * gat_h2f(E5f[(size_t)bh * GN + j])));
        float p = fmaxf(a0, a1);
        l += p;
        for (int cc = 0; cc < 16; cc++)
            accS[cc] += p * gat_h2f(hbb[gat_hswz_idx(chh + cc, j)]);
    }
    float li = 1.0f / l;
    for (int cc = 0; cc < 16; cc++) {
        float v = accS[cc] * li; v = v > 0.f ? v : 0.f;
        size_t oi = ((size_t)(b * GN) + row) * GHF + hh * 64 + chh + cc;
        if (isf) ((float*)outv)[oi] = v;
        else     ((unsigned short*)outv)[oi] = gat_f2bf(v);
    }
#endif
}

// --------------------------------------------------------------------------
extern "C" void kernel_launch(void* const* d_in, const int* in_sizes, int n_in,
                              void* d_out, int out_size, void* d_ws, size_t ws_size,
                              hipStream_t stream) {
    const float* X  = (const float*)d_in[0];
    const float* A  = (const float*)d_in[1];
    const float* W  = (const float*)d_in[2];
    const float* aS = (const float*)d_in[3];
    const float* aN = (const float*)d_in[4];

    char* ws = (char*)d_ws;
    unsigned short* hswz = (unsigned short*)(ws + OFF_HS);
    float* att_s = (float*)(ws + OFF_ATTS);
    unsigned short* Ef  = (unsigned short*)(ws + OFF_EF);
    unsigned short* E5f = (unsigned short*)(ws + OFF_E5F);
    unsigned char* maskB = (unsigned char*)(ws + OFF_MASK);
    float* maxn_arr = (float*)(ws + OFF_MAXN);

    k_gemm1<<<9216, 256, 0, stream>>>(X, W, aS, aN, A,
                                      hswz, att_s, Ef, E5f, maxn_arr, maskB);
    k_attn_av<<<1024, 256, 0, stream>>>((const unsigned int*)maskB, hswz,
                                        att_s, Ef, E5f, maxn_arr,
                                        A, d_out);
}